// Round 1
// baseline (2876.273 us; speedup 1.0000x reference)
//
#include <hip/hip_runtime.h>
#include <math.h>

constexpr int HID = 256;

#define BM 64
#define BN 64
#define BK 32

// ---------------- CSR build ----------------
__global__ void k_deg(const int* __restrict__ dst, int E, int* __restrict__ deg){
    int i = blockIdx.x*blockDim.x + threadIdx.x;
    if (i < E) atomicAdd(&deg[dst[i]], 1);
}

__global__ void k_scan(const int* __restrict__ deg, int N, int* __restrict__ off){
    __shared__ int part[1024];
    int t = threadIdx.x;
    int chunk = (N + 1023) / 1024;
    int s = t * chunk, e = min(s + chunk, N);
    int sum = 0;
    for (int i = s; i < e; i++) sum += deg[i];
    part[t] = sum;
    __syncthreads();
    for (int o = 1; o < 1024; o <<= 1){
        int v = (t >= o) ? part[t - o] : 0;
        __syncthreads();
        part[t] += v;
        __syncthreads();
    }
    int base = (t == 0) ? 0 : part[t - 1];
    for (int i = s; i < e; i++){ off[i] = base; base += deg[i]; }
    if (e == N && s <= N) off[N] = base;
}

__global__ void k_fill(const int* __restrict__ src, const int* __restrict__ dst, int E,
                       const int* __restrict__ off, int* __restrict__ cursor,
                       int* __restrict__ csr_src){
    int i = blockIdx.x*blockDim.x + threadIdx.x;
    if (i < E){
        int d = dst[i];
        int p = off[d] + atomicAdd(&cursor[d], 1);
        csr_src[p] = src[i];
    }
}

// ---------------- aggregation: out[d,:] = sum_{j in in-edges(d)} h[csr[j],:] ----------------
__global__ void k_agg(const float* __restrict__ h, const int* __restrict__ off,
                      const int* __restrict__ csr, float* __restrict__ out, int N){
    int wave = threadIdx.x >> 6;
    int lane = threadIdx.x & 63;
    int d = blockIdx.x * 4 + wave;
    if (d >= N) return;
    int c = lane * 4;
    float4 acc = {0.f, 0.f, 0.f, 0.f};
    int s0 = off[d], s1 = off[d + 1];
    for (int j = s0; j < s1; j++){
        int s = csr[j];
        const float4 v = *(const float4*)(h + (size_t)s * HID + c);
        acc.x += v.x; acc.y += v.y; acc.z += v.z; acc.w += v.w;
    }
    *(float4*)(out + (size_t)d * HID + c) = acc;
}

// ---------------- tiled fp32 GEMM with fused GRU epilogues ----------------
// C = A1 @ B1(^T)  [+ A2 @ B2(^T)]  with epilogue
// EPI 0: C = acc1
// EPI 1: C = sigmoid(acc1 + bias1[c] + acc2 + bias2[c])
// EPI 2: n = tanh(acc1+bias1[c] + R*(acc2+bias2[c])); C = (1-Z)*n + Z*H   (C may alias Rb)
// BT: B is [N,K] (weight layout, compute A@B^T); else B is [K,N]
// GATHER: A1 rows indexed through ridx
template<int EPI, bool DUAL, bool BT, bool GATHER>
__global__ __launch_bounds__(256) void k_gemm(
    const float* __restrict__ A1, const float* __restrict__ A2,
    const float* __restrict__ B1, const float* __restrict__ B2,
    const float* __restrict__ bias1, const float* __restrict__ bias2,
    const float* Rb, const float* __restrict__ Zb, const float* __restrict__ Hb,
    float* C, const int* __restrict__ ridx,
    int M, int N, int K)
{
    __shared__ float As1[BK][BM], Bs1[BK][BN], As2[BK][BM], Bs2[BK][BN];

    int tid = threadIdx.x;
    int tx = tid & 15, ty = tid >> 4;
    int row0 = blockIdx.x * BM, col0 = blockIdx.y * BN;

    float acc1[4][4] = {};
    float acc2[4][4] = {};

    // A staging coords: each thread loads 8 contiguous k's of one row
    int ar = tid >> 2;
    int ak = (tid & 3) * 8;
    int grow = row0 + ar;
    int arow = (grow < M) ? grow : (M - 1);
    long asrc = (long)(GATHER ? ridx[arow] : arow) * K;
    long a2src = (long)arow * K;

    // B staging coords
    int bn, bk;
    if (BT){ bn = tid >> 2; bk = (tid & 3) * 8; }
    else   { bk = tid >> 3; bn = (tid & 7) * 8; }

    for (int k0 = 0; k0 < K; k0 += BK){
        float a1r[8], b1r[8], a2r[8], b2r[8];
        #pragma unroll
        for (int i = 0; i < 8; i++) a1r[i] = A1[asrc + k0 + ak + i];
        if (DUAL){
            #pragma unroll
            for (int i = 0; i < 8; i++) a2r[i] = A2[a2src + k0 + ak + i];
        }
        if (BT){
            const float* bp1 = B1 + (long)(col0 + bn) * K + k0 + bk;
            #pragma unroll
            for (int i = 0; i < 8; i++) b1r[i] = bp1[i];
            if (DUAL){
                const float* bp2 = B2 + (long)(col0 + bn) * K + k0 + bk;
                #pragma unroll
                for (int i = 0; i < 8; i++) b2r[i] = bp2[i];
            }
        } else {
            const float* bp1 = B1 + (long)(k0 + bk) * N + col0 + bn;
            #pragma unroll
            for (int i = 0; i < 8; i++) b1r[i] = bp1[i];
            if (DUAL){
                const float* bp2 = B2 + (long)(k0 + bk) * N + col0 + bn;
                #pragma unroll
                for (int i = 0; i < 8; i++) b2r[i] = bp2[i];
            }
        }

        __syncthreads();
        if (BT){
            #pragma unroll
            for (int i = 0; i < 8; i++) Bs1[bk + i][bn] = b1r[i];
            if (DUAL){
                #pragma unroll
                for (int i = 0; i < 8; i++) Bs2[bk + i][bn] = b2r[i];
            }
        } else {
            #pragma unroll
            for (int i = 0; i < 8; i++) Bs1[bk][bn + i] = b1r[i];
            if (DUAL){
                #pragma unroll
                for (int i = 0; i < 8; i++) Bs2[bk][bn + i] = b2r[i];
            }
        }
        #pragma unroll
        for (int i = 0; i < 8; i++) As1[ak + i][ar] = a1r[i];
        if (DUAL){
            #pragma unroll
            for (int i = 0; i < 8; i++) As2[ak + i][ar] = a2r[i];
        }
        __syncthreads();

        #pragma unroll
        for (int k = 0; k < BK; k++){
            float a1[4], b1[4];
            *(float4*)a1 = *(const float4*)&As1[k][ty * 4];
            *(float4*)b1 = *(const float4*)&Bs1[k][tx * 4];
            float a2[4], b2[4];
            if (DUAL){
                *(float4*)a2 = *(const float4*)&As2[k][ty * 4];
                *(float4*)b2 = *(const float4*)&Bs2[k][tx * 4];
            }
            #pragma unroll
            for (int i = 0; i < 4; i++){
                #pragma unroll
                for (int j = 0; j < 4; j++){
                    acc1[i][j] += a1[i] * b1[j];
                    if (DUAL) acc2[i][j] += a2[i] * b2[j];
                }
            }
        }
    }

    #pragma unroll
    for (int i = 0; i < 4; i++){
        int r = row0 + ty * 4 + i;
        if (r >= M) continue;
        #pragma unroll
        for (int j = 0; j < 4; j++){
            int c = col0 + tx * 4 + j;
            long idx = (long)r * N + c;
            if (EPI == 0){
                C[idx] = acc1[i][j];
            } else if (EPI == 1){
                float x = acc1[i][j] + bias1[c] + acc2[i][j] + bias2[c];
                C[idx] = 1.f / (1.f + __expf(-x));
            } else {
                float g1 = acc1[i][j] + bias1[c];
                float g2 = acc2[i][j] + bias2[c];
                float rr = Rb[idx];
                float zz = Zb[idx];
                float hv = Hb[idx];
                float n = tanhf(g1 + rr * g2);
                C[idx] = (1.f - zz) * n + zz * hv;
            }
        }
    }
}

// ---------------- pool (segment max over sorted batch) + MLP head ----------------
__global__ void k_pool_mlp(const float* __restrict__ h, const int* __restrict__ batch,
                           int Nn, int G,
                           const float* __restrict__ W1, const float* __restrict__ b1,
                           const float* __restrict__ W2, const float* __restrict__ b2,
                           float* __restrict__ out){
    int g = blockIdx.x;
    __shared__ float pool[HID];
    __shared__ float hid[64];

    int lo = 0, hi = Nn;
    while (lo < hi){ int mid = (lo + hi) >> 1; if (batch[mid] < g) lo = mid + 1; else hi = mid; }
    int s = lo;
    lo = s; hi = Nn;
    while (lo < hi){ int mid = (lo + hi) >> 1; if (batch[mid] < g + 1) lo = mid + 1; else hi = mid; }
    int e = lo;

    int c = threadIdx.x;
    float mx = -INFINITY;
    for (int i = s; i < e; i++) mx = fmaxf(mx, h[(size_t)i * HID + c]);
    pool[c] = mx;
    out[(size_t)G + (size_t)g * HID + c] = mx;
    __syncthreads();

    if (c < 64){
        float sacc = b1[c];
        for (int k = 0; k < HID; k++) sacc += pool[k] * W1[c * HID + k];
        hid[c] = fmaxf(sacc, 0.f) * W2[c];
    }
    __syncthreads();
    if (c == 0){
        float sacc = b2[0];
        for (int j = 0; j < 64; j++) sacc += hid[j];
        out[g] = sacc;
    }
}

extern "C" void kernel_launch(void* const* d_in, const int* in_sizes, int n_in,
                              void* d_out, int out_size, void* d_ws, size_t ws_size,
                              hipStream_t stream){
    const int*   x_lex = (const int*)d_in[0];
    const int*   edge  = (const int*)d_in[1];
    const int*   batch = (const int*)d_in[2];
    const float* embed = (const float*)d_in[3];
    const float* Wproj = (const float*)d_in[4];
    const float* Wg    = (const float*)d_in[5];
    const float* Wih   = (const float*)d_in[6];
    const float* bih   = (const float*)d_in[7];
    const float* Whh   = (const float*)d_in[8];
    const float* bhh   = (const float*)d_in[9];
    const float* W1    = (const float*)d_in[10];
    const float* b1    = (const float*)d_in[11];
    const float* W2    = (const float*)d_in[12];
    const float* b2    = (const float*)d_in[13];

    int Nn  = in_sizes[0];
    int E   = in_sizes[1] / 2;
    int G   = out_size / (1 + HID);
    int EMB = in_sizes[4] / HID;   // W_proj is [HID, EMBED]

    const int* esrc = edge;
    const int* edst = edge + E;

    size_t nf = (size_t)Nn * HID;
    float* F0 = (float*)d_ws;
    float* F1 = F0 + nf;
    float* F2 = F1 + nf;
    float* F3 = F2 + nf;
    int* deg    = (int*)(F3 + nf);
    int* cursor = deg + Nn;
    int* off    = cursor + Nn;
    int* csr    = off + Nn + 1;

    size_t needed = 4 * nf * sizeof(float) + (size_t)(3 * Nn + 1 + E) * sizeof(int);
    if (ws_size < needed) return;   // avoid corrupting memory if ws too small

    // CSR by destination
    hipMemsetAsync(deg, 0, sizeof(int) * (size_t)(2 * Nn), stream);  // deg + cursor
    k_deg <<<(E + 255) / 256, 256, 0, stream>>>(edst, E, deg);
    k_scan<<<1, 1024, 0, stream>>>(deg, Nn, off);
    k_fill<<<(E + 255) / 256, 256, 0, stream>>>(esrc, edst, E, off, cursor, csr);

    int mb = (Nn + BM - 1) / BM;
    dim3 g256(mb, HID / BN);

    // h0 = embed[x_lex] @ Wproj^T  -> F0
    k_gemm<0, false, true, true><<<g256, 256, 0, stream>>>(
        embed, nullptr, Wproj, nullptr, nullptr, nullptr,
        nullptr, nullptr, nullptr, F0, x_lex, Nn, HID, EMB);

    float* hcur = F0;
    float* t1 = F1;   // hagg -> R -> h_next
    float* t2 = F2;   // agg
    float* t3 = F3;   // Z

    for (int l = 0; l < 3; l++){
        // hagg = segment_sum(h[src] -> dst)
        k_agg<<<(Nn + 3) / 4, 256, 0, stream>>>(hcur, off, csr, t1, Nn);

        // agg = hagg @ ggnn_weight[l]   (B is [K,N] row-major)
        k_gemm<0, false, false, false><<<g256, 256, 0, stream>>>(
            t1, nullptr, Wg + (size_t)l * HID * HID, nullptr, nullptr, nullptr,
            nullptr, nullptr, nullptr, t2, nullptr, Nn, HID, HID);

        // R = sigmoid(agg@Wih_r^T + b_ih_r + h@Whh_r^T + b_hh_r)  -> t1
        k_gemm<1, true, true, false><<<g256, 256, 0, stream>>>(
            t2, hcur, Wih + 0 * HID * HID, Whh + 0 * HID * HID, bih + 0 * HID, bhh + 0 * HID,
            nullptr, nullptr, nullptr, t1, nullptr, Nn, HID, HID);

        // Z -> t3
        k_gemm<1, true, true, false><<<g256, 256, 0, stream>>>(
            t2, hcur, Wih + 1 * (size_t)HID * HID, Whh + 1 * (size_t)HID * HID, bih + HID, bhh + HID,
            nullptr, nullptr, nullptr, t3, nullptr, Nn, HID, HID);

        // n-gate + blend: h_next = (1-Z)*tanh(gi_n + R*gh_n) + Z*h   -> t1 (overwrites R elementwise)
        k_gemm<2, true, true, false><<<g256, 256, 0, stream>>>(
            t2, hcur, Wih + 2 * (size_t)HID * HID, Whh + 2 * (size_t)HID * HID, bih + 2 * HID, bhh + 2 * HID,
            t1, t3, hcur, t1, nullptr, Nn, HID, HID);

        // swap
        float* tmp = hcur; hcur = t1; t1 = tmp;
    }

    k_pool_mlp<<<G, HID, 0, stream>>>(hcur, batch, Nn, G, W1, b1, W2, b2, (float*)d_out);
}

// Round 2
// 1230.651 us; speedup vs baseline: 2.3372x; 2.3372x over previous
//
#include <hip/hip_runtime.h>
#include <math.h>

constexpr int HID = 256;

typedef __attribute__((ext_vector_type(8))) short bf16x8;
typedef __attribute__((ext_vector_type(4))) float f32x4;

__device__ __forceinline__ float bf2f(unsigned short u){
    union { unsigned int i; float f; } v; v.i = ((unsigned int)u) << 16; return v.f;
}
__device__ __forceinline__ unsigned short f2bf(float f){
    union { float f; unsigned int i; } v; v.f = f;
    return (unsigned short)((v.i + 0x7fffu + ((v.i >> 16) & 1u)) >> 16);
}

// ---------------- casts ----------------
__global__ void k_cast(const float* __restrict__ in, unsigned short* __restrict__ out, int n){
    int i = blockIdx.x*blockDim.x + threadIdx.x;
    if (i < n) out[i] = f2bf(in[i]);
}
// WgT[l][n][k] = Wg[l][k][n]
__global__ void k_castT(const float* __restrict__ in, unsigned short* __restrict__ out, int L){
    int i = blockIdx.x*blockDim.x + threadIdx.x;
    int tot = L*HID*HID;
    if (i < tot){
        int l = i / (HID*HID);
        int r = i % (HID*HID);
        int n = r / HID, k = r % HID;
        out[i] = f2bf(in[(size_t)l*HID*HID + (size_t)k*HID + n]);
    }
}
__global__ void k_gather_cast(const float* __restrict__ embed, const int* __restrict__ idx,
                              unsigned short* __restrict__ x0, int Nn, int EMB){
    int i = blockIdx.x*blockDim.x + threadIdx.x;
    if (i < Nn*EMB){
        int row = i / EMB, k = i % EMB;
        x0[i] = f2bf(embed[(size_t)idx[row]*EMB + k]);
    }
}

// ---------------- CSR build ----------------
__global__ void k_deg(const int* __restrict__ dst, int E, int* __restrict__ deg){
    int i = blockIdx.x*blockDim.x + threadIdx.x;
    if (i < E) atomicAdd(&deg[dst[i]], 1);
}

__global__ void k_scan(const int* __restrict__ deg, int N, int* __restrict__ off){
    __shared__ int part[1024];
    int t = threadIdx.x;
    int chunk = (N + 1023) / 1024;
    int s = t * chunk, e = min(s + chunk, N);
    int sum = 0;
    for (int i = s; i < e; i++) sum += deg[i];
    part[t] = sum;
    __syncthreads();
    for (int o = 1; o < 1024; o <<= 1){
        int v = (t >= o) ? part[t - o] : 0;
        __syncthreads();
        part[t] += v;
        __syncthreads();
    }
    int base = (t == 0) ? 0 : part[t - 1];
    for (int i = s; i < e; i++){ off[i] = base; base += deg[i]; }
    if (e == N && s <= N) off[N] = base;
}

__global__ void k_fill(const int* __restrict__ src, const int* __restrict__ dst, int E,
                       const int* __restrict__ off, int* __restrict__ cursor,
                       int* __restrict__ csr_src){
    int i = blockIdx.x*blockDim.x + threadIdx.x;
    if (i < E){
        int d = dst[i];
        int p = off[d] + atomicAdd(&cursor[d], 1);
        csr_src[p] = src[i];
    }
}

// ---------------- aggregation: out[d,:] = sum_{j in in-edges(d)} h[csr[j],:] (bf16 in/out, fp32 acc) ----------------
__global__ void k_agg(const unsigned short* __restrict__ h, const int* __restrict__ off,
                      const int* __restrict__ csr, unsigned short* __restrict__ out, int N){
    int wave = threadIdx.x >> 6, lane = threadIdx.x & 63;
    int d = blockIdx.x * 4 + wave;
    if (d >= N) return;
    int c = lane * 4;
    float a0 = 0.f, a1 = 0.f, a2 = 0.f, a3 = 0.f;
    int s0 = off[d], s1 = off[d + 1];
    for (int j = s0; j < s1; j++){
        int s = csr[j];
        ushort4 v = *(const ushort4*)(h + (size_t)s * HID + c);
        a0 += bf2f(v.x); a1 += bf2f(v.y); a2 += bf2f(v.z); a3 += bf2f(v.w);
    }
    ushort4 o; o.x = f2bf(a0); o.y = f2bf(a1); o.z = f2bf(a2); o.w = f2bf(a3);
    *(ushort4*)(out + (size_t)d * HID + c) = o;
}

// ---------------- bf16 MFMA GEMM: C = A1 @ B1^T [(+ A2 @ B2^T)], B given as [N,K] row-major ----------------
// EPI 0: C = acc                        (single source)
// EPI 1: C = sigmoid(acc1+acc2 + b1[c]+b2[c])   (dual source, MERGED accumulator)
// EPI 2: g1=acc1+b1[c], g2=acc2+b2[c]; r=RZ[row,c], z=RZ[row,N+c], hv=Hb[row,c];
//        C = (1-z)*tanh(g1 + r*g2) + z*hv        (dual source, dual accumulator)
// LDS tiles [128 rows][32 k] bf16, 16B-chunk swizzle: chunk' = chunk ^ ((row>>1)&3)
template<int EPI, bool DUAL>
__global__ __launch_bounds__(256) void k_mm(
    const unsigned short* __restrict__ A1, const unsigned short* __restrict__ A2,
    const unsigned short* __restrict__ B1, const unsigned short* __restrict__ B2,
    const float* __restrict__ bias1, const float* __restrict__ bias2,
    const unsigned short* __restrict__ RZ, const unsigned short* __restrict__ Hb,
    unsigned short* __restrict__ C, int M, int N, int K)
{
    constexpr int NT = DUAL ? 4 : 2;
    __shared__ __align__(16) unsigned short smem[NT * 128 * 32];
    unsigned short* As1 = smem;
    unsigned short* Bs1 = smem + 4096;
    unsigned short* As2 = DUAL ? (smem + 8192)  : nullptr;
    unsigned short* Bs2 = DUAL ? (smem + 12288) : nullptr;

    int tid = threadIdx.x;
    int w  = tid >> 6, l = tid & 63;
    int wm = w >> 1,  wn = w & 1;
    int lr = l & 15,  lk = l >> 4;
    long row0 = (long)blockIdx.x * 128;
    int  col0 = blockIdx.y * 128;

    // staging: 512 16B-slots per tile; thread t handles slots t and t+256
    int  sdst[2];
    long aoff[2], boff[2];
    #pragma unroll
    for (int s = 0; s < 2; s++){
        int o = tid + s * 256;
        int row = o >> 2, kc = o & 3;
        sdst[s] = row * 4 + (kc ^ ((row >> 1) & 3));
        long gr = row0 + row; if (gr > M - 1) gr = M - 1;
        aoff[s] = gr * (long)K + kc * 8;
        boff[s] = (long)(col0 + row) * K + kc * 8;
    }

    f32x4 acc[4][4] = {};
    f32x4 acc2[4][4] = {};

    for (int k0 = 0; k0 < K; k0 += 32){
        bf16x8 va1[2], vb1[2], va2[2], vb2[2];
        #pragma unroll
        for (int s = 0; s < 2; s++){
            va1[s] = *(const bf16x8*)(A1 + aoff[s] + k0);
            vb1[s] = *(const bf16x8*)(B1 + boff[s] + k0);
            if (DUAL){
                va2[s] = *(const bf16x8*)(A2 + aoff[s] + k0);
                vb2[s] = *(const bf16x8*)(B2 + boff[s] + k0);
            }
        }
        __syncthreads();
        #pragma unroll
        for (int s = 0; s < 2; s++){
            *(bf16x8*)(As1 + (size_t)sdst[s] * 8) = va1[s];
            *(bf16x8*)(Bs1 + (size_t)sdst[s] * 8) = vb1[s];
            if (DUAL){
                *(bf16x8*)(As2 + (size_t)sdst[s] * 8) = va2[s];
                *(bf16x8*)(Bs2 + (size_t)sdst[s] * 8) = vb2[s];
            }
        }
        __syncthreads();

        bf16x8 af[4], bf[4];
        #pragma unroll
        for (int i = 0; i < 4; i++){
            int ra = wm * 64 + i * 16 + lr;
            af[i] = *(const bf16x8*)(As1 + (size_t)(ra * 4 + (lk ^ ((ra >> 1) & 3))) * 8);
            int rb = wn * 64 + i * 16 + lr;
            bf[i] = *(const bf16x8*)(Bs1 + (size_t)(rb * 4 + (lk ^ ((rb >> 1) & 3))) * 8);
        }
        #pragma unroll
        for (int mi = 0; mi < 4; mi++)
            #pragma unroll
            for (int ni = 0; ni < 4; ni++)
                acc[mi][ni] = __builtin_amdgcn_mfma_f32_16x16x32_bf16(af[mi], bf[ni], acc[mi][ni], 0, 0, 0);

        if (DUAL){
            bf16x8 af2[4], bf2v[4];
            #pragma unroll
            for (int i = 0; i < 4; i++){
                int ra = wm * 64 + i * 16 + lr;
                af2[i] = *(const bf16x8*)(As2 + (size_t)(ra * 4 + (lk ^ ((ra >> 1) & 3))) * 8);
                int rb = wn * 64 + i * 16 + lr;
                bf2v[i] = *(const bf16x8*)(Bs2 + (size_t)(rb * 4 + (lk ^ ((rb >> 1) & 3))) * 8);
            }
            #pragma unroll
            for (int mi = 0; mi < 4; mi++)
                #pragma unroll
                for (int ni = 0; ni < 4; ni++){
                    if (EPI == 1)
                        acc[mi][ni]  = __builtin_amdgcn_mfma_f32_16x16x32_bf16(af2[mi], bf2v[ni], acc[mi][ni], 0, 0, 0);
                    else
                        acc2[mi][ni] = __builtin_amdgcn_mfma_f32_16x16x32_bf16(af2[mi], bf2v[ni], acc2[mi][ni], 0, 0, 0);
                }
        }
        __syncthreads();
    }

    // epilogue: D[row][col], row = (lane>>4)*4 + reg, col = lane&15 per 16x16 frag
    #pragma unroll
    for (int mi = 0; mi < 4; mi++)
        #pragma unroll
        for (int ni = 0; ni < 4; ni++)
            #pragma unroll
            for (int r = 0; r < 4; r++){
                long row = row0 + wm * 64 + mi * 16 + lk * 4 + r;
                int  col = col0 + wn * 64 + ni * 16 + lr;
                if (row < M){
                    float v = acc[mi][ni][r];
                    if (EPI == 0){
                        C[row * N + col] = f2bf(v);
                    } else if (EPI == 1){
                        float x = v + bias1[col] + bias2[col];
                        C[row * N + col] = f2bf(1.f / (1.f + __expf(-x)));
                    } else {
                        float g1 = v + bias1[col];
                        float g2 = acc2[mi][ni][r] + bias2[col];
                        float rr = bf2f(RZ[row * 2 * N + col]);
                        float zz = bf2f(RZ[row * 2 * N + N + col]);
                        float hv = bf2f(Hb[row * N + col]);
                        float nn = tanhf(g1 + rr * g2);
                        C[row * N + col] = f2bf((1.f - zz) * nn + zz * hv);
                    }
                }
            }
}

// ---------------- pool (segment max over sorted batch) + MLP head ----------------
__global__ void k_pool_mlp(const unsigned short* __restrict__ h, const int* __restrict__ batch,
                           int Nn, int G,
                           const float* __restrict__ W1, const float* __restrict__ b1,
                           const float* __restrict__ W2, const float* __restrict__ b2,
                           float* __restrict__ out){
    int g = blockIdx.x;
    __shared__ float pool[HID];
    __shared__ float hid[64];

    int lo = 0, hi = Nn;
    while (lo < hi){ int mid = (lo + hi) >> 1; if (batch[mid] < g) lo = mid + 1; else hi = mid; }
    int s = lo;
    lo = s; hi = Nn;
    while (lo < hi){ int mid = (lo + hi) >> 1; if (batch[mid] < g + 1) lo = mid + 1; else hi = mid; }
    int e = lo;

    int c = threadIdx.x;
    float mx = -INFINITY;
    for (int i = s; i < e; i++) mx = fmaxf(mx, bf2f(h[(size_t)i * HID + c]));
    pool[c] = mx;
    out[(size_t)G + (size_t)g * HID + c] = mx;
    __syncthreads();

    if (c < 64){
        float sacc = b1[c];
        for (int k = 0; k < HID; k++) sacc += pool[k] * W1[c * HID + k];
        hid[c] = fmaxf(sacc, 0.f) * W2[c];
    }
    __syncthreads();
    if (c == 0){
        float sacc = b2[0];
        for (int j = 0; j < 64; j++) sacc += hid[j];
        out[g] = sacc;
    }
}

extern "C" void kernel_launch(void* const* d_in, const int* in_sizes, int n_in,
                              void* d_out, int out_size, void* d_ws, size_t ws_size,
                              hipStream_t stream){
    const int*   x_lex = (const int*)d_in[0];
    const int*   edge  = (const int*)d_in[1];
    const int*   batch = (const int*)d_in[2];
    const float* embed = (const float*)d_in[3];
    const float* Wproj = (const float*)d_in[4];
    const float* Wg    = (const float*)d_in[5];
    const float* Wih   = (const float*)d_in[6];
    const float* bih   = (const float*)d_in[7];
    const float* Whh   = (const float*)d_in[8];
    const float* bhh   = (const float*)d_in[9];
    const float* W1    = (const float*)d_in[10];
    const float* b1    = (const float*)d_in[11];
    const float* W2    = (const float*)d_in[12];
    const float* b2    = (const float*)d_in[13];

    int Nn  = in_sizes[0];
    int E   = in_sizes[1] / 2;
    int G   = out_size / (1 + HID);
    int EMB = in_sizes[4] / HID;   // W_proj is [HID, EMBED]

    const int* esrc = edge;
    const int* edst = edge + E;

    unsigned short* x0    = (unsigned short*)d_ws;
    unsigned short* hA    = x0    + (size_t)Nn * EMB;
    unsigned short* hB    = hA    + (size_t)Nn * HID;
    unsigned short* aggh  = hB    + (size_t)Nn * HID;
    unsigned short* msgb  = aggh  + (size_t)Nn * HID;
    unsigned short* rz    = msgb  + (size_t)Nn * HID;
    unsigned short* wproj = rz    + (size_t)Nn * 2 * HID;
    unsigned short* wih   = wproj + (size_t)HID * EMB;
    unsigned short* whh   = wih   + (size_t)3 * HID * HID;
    unsigned short* wgT   = whh   + (size_t)3 * HID * HID;
    int* deg    = (int*)(wgT + (size_t)3 * HID * HID);
    int* cursor = deg + Nn;
    int* off    = cursor + Nn;
    int* csr    = off + Nn + 1;

    size_t ush = (size_t)Nn * (EMB + 4 * HID + 2 * HID) + (size_t)HID * EMB + (size_t)9 * HID * HID;
    size_t needed = ush * 2 + (size_t)(3 * Nn + 1 + E) * sizeof(int);
    if (ws_size < needed) return;

    // CSR by destination
    hipMemsetAsync(deg, 0, sizeof(int) * (size_t)(2 * Nn), stream);
    k_deg <<<(E + 255) / 256, 256, 0, stream>>>(edst, E, deg);
    k_scan<<<1, 1024, 0, stream>>>(deg, Nn, off);
    k_fill<<<(E + 255) / 256, 256, 0, stream>>>(esrc, edst, E, off, cursor, csr);

    // weight casts
    k_cast <<<(HID * EMB + 255) / 256, 256, 0, stream>>>(Wproj, wproj, HID * EMB);
    k_cast <<<(3 * HID * HID + 255) / 256, 256, 0, stream>>>(Wih, wih, 3 * HID * HID);
    k_cast <<<(3 * HID * HID + 255) / 256, 256, 0, stream>>>(Whh, whh, 3 * HID * HID);
    k_castT<<<(3 * HID * HID + 255) / 256, 256, 0, stream>>>(Wg, wgT, 3);
    k_gather_cast<<<(Nn * EMB + 255) / 256, 256, 0, stream>>>(embed, x_lex, x0, Nn, EMB);

    int mb = (Nn + 127) / 128;

    // h0 = x0 @ wproj^T
    k_mm<0, false><<<dim3(mb, HID / 128), 256, 0, stream>>>(
        x0, nullptr, wproj, nullptr, nullptr, nullptr, nullptr, nullptr, hA, Nn, HID, EMB);

    unsigned short* hc = hA;
    unsigned short* hn = hB;
    for (int lay = 0; lay < 3; lay++){
        // aggh = segment_sum(h[src] -> dst)
        k_agg<<<(Nn + 3) / 4, 256, 0, stream>>>(hc, off, csr, aggh, Nn);
        // msg = aggh @ Wg  (wgT is [n][k])
        k_mm<0, false><<<dim3(mb, HID / 128), 256, 0, stream>>>(
            aggh, nullptr, wgT + (size_t)lay * HID * HID, nullptr, nullptr, nullptr,
            nullptr, nullptr, msgb, Nn, HID, HID);
        // RZ = sigmoid(msg@Wih_rz^T + h@Whh_rz^T + biases), N=512
        k_mm<1, true><<<dim3(mb, 2 * HID / 128), 256, 0, stream>>>(
            msgb, hc, wih, whh, bih, bhh, nullptr, nullptr, rz, Nn, 2 * HID, HID);
        // h_next = (1-z)*tanh(gin + r*ghn) + z*h
        k_mm<2, true><<<dim3(mb, HID / 128), 256, 0, stream>>>(
            msgb, hc, wih + (size_t)2 * HID * HID, whh + (size_t)2 * HID * HID,
            bih + 2 * HID, bhh + 2 * HID, rz, hc, hn, Nn, HID, HID);
        unsigned short* t = hc; hc = hn; hn = t;
    }

    k_pool_mlp<<<G, HID, 0, stream>>>(hc, batch, Nn, G, W1, b1, W2, b2, (float*)d_out);
}

// Round 3
// 855.877 us; speedup vs baseline: 3.3606x; 1.4379x over previous
//
#include <hip/hip_runtime.h>
#include <math.h>

constexpr int HID = 256;

typedef __attribute__((ext_vector_type(8))) short bf16x8;
typedef __attribute__((ext_vector_type(4))) float f32x4;

__device__ __forceinline__ float bf2f(unsigned short u){
    union { unsigned int i; float f; } v; v.i = ((unsigned int)u) << 16; return v.f;
}
__device__ __forceinline__ unsigned short f2bf(float f){
    union { float f; unsigned int i; } v; v.f = f;
    return (unsigned short)((v.i + 0x7fffu + ((v.i >> 16) & 1u)) >> 16);
}
__device__ __forceinline__ float sigm(float x){ return 1.f / (1.f + __expf(-x)); }

// async global->LDS, 16B per lane. lds dest must be wave-uniform base; HW adds lane*16.
__device__ __forceinline__ void gll16(const unsigned short* g, unsigned short* l){
    __builtin_amdgcn_global_load_lds(
        (const __attribute__((address_space(1))) void*)g,
        (__attribute__((address_space(3))) void*)l, 16, 0, 0);
}

// ---------------- casts ----------------
__global__ void k_cast(const float* __restrict__ in, unsigned short* __restrict__ out, int n){
    int i = blockIdx.x*blockDim.x + threadIdx.x;
    if (i < n) out[i] = f2bf(in[i]);
}
__global__ void k_castT(const float* __restrict__ in, unsigned short* __restrict__ out, int L){
    int i = blockIdx.x*blockDim.x + threadIdx.x;
    int tot = L*HID*HID;
    if (i < tot){
        int l = i / (HID*HID);
        int r = i % (HID*HID);
        int n = r / HID, k = r % HID;
        out[i] = f2bf(in[(size_t)l*HID*HID + (size_t)k*HID + n]);
    }
}
__global__ void k_gather_cast(const float* __restrict__ embed, const int* __restrict__ idx,
                              unsigned short* __restrict__ x0, int Nn, int EMB){
    int i = blockIdx.x*blockDim.x + threadIdx.x;
    if (i < Nn*EMB){
        int row = i / EMB, k = i % EMB;
        x0[i] = f2bf(embed[(size_t)idx[row]*EMB + k]);
    }
}

// ---------------- CSR build ----------------
__global__ void k_deg(const int* __restrict__ dst, int E, int* __restrict__ deg){
    int i = blockIdx.x*blockDim.x + threadIdx.x;
    if (i < E) atomicAdd(&deg[dst[i]], 1);
}

__global__ void k_scan(const int* __restrict__ deg, int N, int* __restrict__ off){
    __shared__ int part[1024];
    int t = threadIdx.x;
    int chunk = (N + 1023) / 1024;
    int s = t * chunk, e = min(s + chunk, N);
    int sum = 0;
    for (int i = s; i < e; i++) sum += deg[i];
    part[t] = sum;
    __syncthreads();
    for (int o = 1; o < 1024; o <<= 1){
        int v = (t >= o) ? part[t - o] : 0;
        __syncthreads();
        part[t] += v;
        __syncthreads();
    }
    int base = (t == 0) ? 0 : part[t - 1];
    for (int i = s; i < e; i++){ off[i] = base; base += deg[i]; }
    if (e == N && s <= N) off[N] = base;
}

__global__ void k_fill(const int* __restrict__ src, const int* __restrict__ dst, int E,
                       const int* __restrict__ off, int* __restrict__ cursor,
                       int* __restrict__ csr_src){
    int i = blockIdx.x*blockDim.x + threadIdx.x;
    if (i < E){
        int d = dst[i];
        int p = off[d] + atomicAdd(&cursor[d], 1);
        csr_src[p] = src[i];
    }
}

// ---------------- aggregation (bf16 in/out, fp32 acc), 2-unrolled for MLP ----------------
__global__ void k_agg(const unsigned short* __restrict__ h, const int* __restrict__ off,
                      const int* __restrict__ csr, unsigned short* __restrict__ out, int N){
    int wave = threadIdx.x >> 6, lane = threadIdx.x & 63;
    int d = blockIdx.x * 4 + wave;
    if (d >= N) return;
    int c = lane * 4;
    float a0 = 0.f, a1 = 0.f, a2 = 0.f, a3 = 0.f;
    int s0 = off[d], s1 = off[d + 1];
    int j = s0;
    for (; j + 1 < s1; j += 2){
        int sA = csr[j], sB = csr[j + 1];
        ushort4 vA = *(const ushort4*)(h + (size_t)sA * HID + c);
        ushort4 vB = *(const ushort4*)(h + (size_t)sB * HID + c);
        a0 += bf2f(vA.x) + bf2f(vB.x);
        a1 += bf2f(vA.y) + bf2f(vB.y);
        a2 += bf2f(vA.z) + bf2f(vB.z);
        a3 += bf2f(vA.w) + bf2f(vB.w);
    }
    if (j < s1){
        int sA = csr[j];
        ushort4 vA = *(const ushort4*)(h + (size_t)sA * HID + c);
        a0 += bf2f(vA.x); a1 += bf2f(vA.y); a2 += bf2f(vA.z); a3 += bf2f(vA.w);
    }
    ushort4 o; o.x = f2bf(a0); o.y = f2bf(a1); o.z = f2bf(a2); o.w = f2bf(a3);
    *(ushort4*)(out + (size_t)d * HID + c) = o;
}

// ---------------- single-source GEMM: C = A @ B^T, B is [N][K] row-major, bf16 ----------------
// BM=128, BN=128, BK=32, 256 thr / 4 waves (2x2), wave tile 64x64.
// global_load_lds double-buffered, XOR chunk swizzle on the GLOBAL source (LDS linear).
__global__ __launch_bounds__(256, 3) void k_mmS(
    const unsigned short* __restrict__ A, const unsigned short* __restrict__ B,
    unsigned short* __restrict__ C, int M, int N, int K)
{
    __shared__ __align__(16) unsigned short sm[2 * 1024 * 8];  // 2 buf x 1024 slots x 16B
    const int tid = threadIdx.x, w = tid >> 6, l = tid & 63;
    const int wm = w >> 1, wn = w & 1, lr = l & 15, lk = l >> 4;
    const long row0 = (long)blockIdx.x * 128;
    const int  col0 = blockIdx.y * 128;

    const unsigned short* ap[2];
    const unsigned short* bp[2];
    #pragma unroll
    for (int s = 0; s < 2; s++){
        int c = s * 256 + tid, row = c >> 2, ks = c & 3;
        long ga = row0 + row; if (ga > M - 1) ga = M - 1;
        int sw = ks ^ ((row >> 1) & 3);
        ap[s] = A + ga * (long)K + sw * 8;
        bp[s] = B + (long)(col0 + row) * K + sw * 8;
    }

    const int NT = K >> 5;
    #pragma unroll
    for (int s = 0; s < 2; s++){
        gll16(ap[s], sm + (s * 256 + w * 64) * 8);
        gll16(bp[s], sm + (512 + s * 256 + w * 64) * 8);
    }
    __syncthreads();

    f32x4 acc[4][4] = {};
    for (int t = 0; t < NT; t++){
        const int cur = t & 1;
        if (t + 1 < NT){
            const int nb = cur ^ 1;
            const int k0 = (t + 1) * 32;
            #pragma unroll
            for (int s = 0; s < 2; s++){
                gll16(ap[s] + k0, sm + (nb * 1024 + s * 256 + w * 64) * 8);
                gll16(bp[s] + k0, sm + (nb * 1024 + 512 + s * 256 + w * 64) * 8);
            }
        }
        const unsigned short* As = sm + cur * 8192;
        const unsigned short* Bs = As + 4096;
        bf16x8 af[4], bfb[4];
        #pragma unroll
        for (int i = 0; i < 4; i++){
            int ra = wm * 64 + i * 16 + lr;
            af[i]  = *(const bf16x8*)(As + (ra * 4 + (lk ^ ((ra >> 1) & 3))) * 8);
            int rb = wn * 64 + i * 16 + lr;
            bfb[i] = *(const bf16x8*)(Bs + (rb * 4 + (lk ^ ((rb >> 1) & 3))) * 8);
        }
        #pragma unroll
        for (int mi = 0; mi < 4; mi++)
            #pragma unroll
            for (int ni = 0; ni < 4; ni++)
                acc[mi][ni] = __builtin_amdgcn_mfma_f32_16x16x32_bf16(af[mi], bfb[ni], acc[mi][ni], 0, 0, 0);
        __syncthreads();
    }

    #pragma unroll
    for (int mi = 0; mi < 4; mi++)
        #pragma unroll
        for (int ni = 0; ni < 4; ni++)
            #pragma unroll
            for (int r = 0; r < 4; r++){
                long row = row0 + wm * 64 + mi * 16 + lk * 4 + r;
                if (row < M){
                    int col = col0 + wn * 64 + ni * 16 + lr;
                    C[row * (long)N + col] = f2bf(acc[mi][ni][r]);
                }
            }
}

// ---------------- fused GRU: h' = (1-z)*tanh(i_n + r*h_n) + z*h for a 128x64 col-slice ----------------
// 4 accumulator sets over shared A-operands (MSG, H):
//   accR = MSG@Wih_r^T + H@Whh_r^T ; accZ likewise ; accI = MSG@Wih_n^T ; accHn = H@Whh_n^T
// B slices staged: 0..2 = Wih gates r,z,n rows [gate*256+c0 .. +64); 3..5 = Whh same.
// 256 thr / 4 waves (2x2), wave tile 64x32 per set. K=256 fixed, BK=32 (8 steps), dbuf.
__global__ __launch_bounds__(256, 2) void k_gru(
    const unsigned short* __restrict__ MSG, const unsigned short* __restrict__ H,
    const unsigned short* __restrict__ WIH, const unsigned short* __restrict__ WHH,
    const float* __restrict__ bih, const float* __restrict__ bhh,
    unsigned short* __restrict__ HN, int M)
{
    constexpr int K = HID;
    // per buffer: A1 512 slots | A2 512 | B 6*256 -> 2560 slots x 16B = 40960 B; x2 = 80 KiB
    __shared__ __align__(16) unsigned short sm[2 * 2560 * 8];
    const int tid = threadIdx.x, w = tid >> 6, l = tid & 63;
    const int wm = w >> 1, wn = w & 1, lr = l & 15, lk = l >> 4;
    const long row0 = (long)blockIdx.x * 128;
    const int  c0 = blockIdx.y * 64;

    const unsigned short* a1p[2];
    const unsigned short* a2p[2];
    const unsigned short* bp[6];
    #pragma unroll
    for (int s = 0; s < 2; s++){
        int c = s * 256 + tid, row = c >> 2, ks = c & 3;
        long ga = row0 + row; if (ga > M - 1) ga = M - 1;
        long o = ga * (long)K + (ks ^ ((row >> 1) & 3)) * 8;
        a1p[s] = MSG + o;
        a2p[s] = H + o;
    }
    {
        int r = tid >> 2, ks = tid & 3;
        int sw = (ks ^ ((r >> 1) & 3)) * 8;
        #pragma unroll
        for (int j = 0; j < 6; j++){
            int gate = (j < 3) ? j : j - 3;
            const unsigned short* W = (j < 3) ? WIH : WHH;
            bp[j] = W + (long)(gate * HID + c0 + r) * K + sw;
        }
    }

    // prologue: stage buffer 0, k0 = 0
    #pragma unroll
    for (int s = 0; s < 2; s++){
        gll16(a1p[s], sm + (s * 256 + w * 64) * 8);
        gll16(a2p[s], sm + (512 + s * 256 + w * 64) * 8);
    }
    #pragma unroll
    for (int j = 0; j < 6; j++)
        gll16(bp[j], sm + (1024 + j * 256 + w * 64) * 8);
    __syncthreads();

    f32x4 aR[4][2] = {}, aZ[4][2] = {}, aI[4][2] = {}, aHn[4][2] = {};

    for (int t = 0; t < 8; t++){
        const int cur = t & 1;
        if (t < 7){
            const int nb = cur ^ 1;
            const int k0 = (t + 1) * 32;
            #pragma unroll
            for (int s = 0; s < 2; s++){
                gll16(a1p[s] + k0, sm + (nb * 2560 + s * 256 + w * 64) * 8);
                gll16(a2p[s] + k0, sm + (nb * 2560 + 512 + s * 256 + w * 64) * 8);
            }
            #pragma unroll
            for (int j = 0; j < 6; j++)
                gll16(bp[j] + k0, sm + (nb * 2560 + 1024 + j * 256 + w * 64) * 8);
        }
        const unsigned short* As1 = sm + cur * 20480;
        const unsigned short* As2 = As1 + 4096;
        const unsigned short* Bs  = As1 + 8192;

        bf16x8 a1[4], a2[4];
        #pragma unroll
        for (int i = 0; i < 4; i++){
            int ra = wm * 64 + i * 16 + lr;
            int sa = (ra * 4 + (lk ^ ((ra >> 1) & 3))) * 8;
            a1[i] = *(const bf16x8*)(As1 + sa);
            a2[i] = *(const bf16x8*)(As2 + sa);
        }
        #pragma unroll
        for (int ni = 0; ni < 2; ni++){
            int rb = wn * 32 + ni * 16 + lr;
            int sb = (rb * 4 + (lk ^ ((rb >> 1) & 3))) * 8;
            bf16x8 bir = *(const bf16x8*)(Bs + 0 * 2048 + sb);
            bf16x8 biz = *(const bf16x8*)(Bs + 1 * 2048 + sb);
            bf16x8 bin = *(const bf16x8*)(Bs + 2 * 2048 + sb);
            bf16x8 bhr = *(const bf16x8*)(Bs + 3 * 2048 + sb);
            bf16x8 bhz = *(const bf16x8*)(Bs + 4 * 2048 + sb);
            bf16x8 bhn = *(const bf16x8*)(Bs + 5 * 2048 + sb);
            #pragma unroll
            for (int mi = 0; mi < 4; mi++){
                aR[mi][ni]  = __builtin_amdgcn_mfma_f32_16x16x32_bf16(a1[mi], bir, aR[mi][ni], 0, 0, 0);
                aR[mi][ni]  = __builtin_amdgcn_mfma_f32_16x16x32_bf16(a2[mi], bhr, aR[mi][ni], 0, 0, 0);
                aZ[mi][ni]  = __builtin_amdgcn_mfma_f32_16x16x32_bf16(a1[mi], biz, aZ[mi][ni], 0, 0, 0);
                aZ[mi][ni]  = __builtin_amdgcn_mfma_f32_16x16x32_bf16(a2[mi], bhz, aZ[mi][ni], 0, 0, 0);
                aI[mi][ni]  = __builtin_amdgcn_mfma_f32_16x16x32_bf16(a1[mi], bin, aI[mi][ni], 0, 0, 0);
                aHn[mi][ni] = __builtin_amdgcn_mfma_f32_16x16x32_bf16(a2[mi], bhn, aHn[mi][ni], 0, 0, 0);
            }
        }
        __syncthreads();
    }

    #pragma unroll
    for (int ni = 0; ni < 2; ni++){
        int gc = c0 + wn * 32 + ni * 16 + lr;
        float br  = bih[gc] + bhh[gc];
        float bz  = bih[HID + gc] + bhh[HID + gc];
        float bin = bih[2 * HID + gc];
        float bhn = bhh[2 * HID + gc];
        #pragma unroll
        for (int mi = 0; mi < 4; mi++)
            #pragma unroll
            for (int r = 0; r < 4; r++){
                long row = row0 + wm * 64 + mi * 16 + lk * 4 + r;
                if (row < M){
                    float rr = sigm(aR[mi][ni][r] + br);
                    float zz = sigm(aZ[mi][ni][r] + bz);
                    float nn = tanhf(aI[mi][ni][r] + bin + rr * (aHn[mi][ni][r] + bhn));
                    float hv = bf2f(H[row * HID + gc]);
                    HN[row * HID + gc] = f2bf((1.f - zz) * nn + zz * hv);
                }
            }
    }
}

// ---------------- pool (segment max over sorted batch) + MLP head ----------------
__global__ void k_pool_mlp(const unsigned short* __restrict__ h, const int* __restrict__ batch,
                           int Nn, int G,
                           const float* __restrict__ W1, const float* __restrict__ b1,
                           const float* __restrict__ W2, const float* __restrict__ b2,
                           float* __restrict__ out){
    int g = blockIdx.x;
    __shared__ float pool[HID];
    __shared__ float hid[64];

    int lo = 0, hi = Nn;
    while (lo < hi){ int mid = (lo + hi) >> 1; if (batch[mid] < g) lo = mid + 1; else hi = mid; }
    int s = lo;
    lo = s; hi = Nn;
    while (lo < hi){ int mid = (lo + hi) >> 1; if (batch[mid] < g + 1) lo = mid + 1; else hi = mid; }
    int e = lo;

    int c = threadIdx.x;
    float mx = -INFINITY;
    for (int i = s; i < e; i++) mx = fmaxf(mx, bf2f(h[(size_t)i * HID + c]));
    pool[c] = mx;
    out[(size_t)G + (size_t)g * HID + c] = mx;
    __syncthreads();

    if (c < 64){
        float sacc = b1[c];
        for (int k = 0; k < HID; k++) sacc += pool[k] * W1[c * HID + k];
        hid[c] = fmaxf(sacc, 0.f) * W2[c];
    }
    __syncthreads();
    if (c == 0){
        float sacc = b2[0];
        for (int j = 0; j < 64; j++) sacc += hid[j];
        out[g] = sacc;
    }
}

extern "C" void kernel_launch(void* const* d_in, const int* in_sizes, int n_in,
                              void* d_out, int out_size, void* d_ws, size_t ws_size,
                              hipStream_t stream){
    const int*   x_lex = (const int*)d_in[0];
    const int*   edge  = (const int*)d_in[1];
    const int*   batch = (const int*)d_in[2];
    const float* embed = (const float*)d_in[3];
    const float* Wproj = (const float*)d_in[4];
    const float* Wg    = (const float*)d_in[5];
    const float* Wih   = (const float*)d_in[6];
    const float* bih   = (const float*)d_in[7];
    const float* Whh   = (const float*)d_in[8];
    const float* bhh   = (const float*)d_in[9];
    const float* W1    = (const float*)d_in[10];
    const float* b1    = (const float*)d_in[11];
    const float* W2    = (const float*)d_in[12];
    const float* b2    = (const float*)d_in[13];

    int Nn  = in_sizes[0];
    int E   = in_sizes[1] / 2;
    int G   = out_size / (1 + HID);
    int EMB = in_sizes[4] / HID;   // W_proj is [HID, EMBED]

    const int* esrc = edge;
    const int* edst = edge + E;

    unsigned short* x0    = (unsigned short*)d_ws;
    unsigned short* hA    = x0    + (size_t)Nn * EMB;
    unsigned short* hB    = hA    + (size_t)Nn * HID;
    unsigned short* aggh  = hB    + (size_t)Nn * HID;
    unsigned short* msgb  = aggh  + (size_t)Nn * HID;
    unsigned short* wproj = msgb  + (size_t)Nn * HID;
    unsigned short* wih   = wproj + (size_t)HID * EMB;
    unsigned short* whh   = wih   + (size_t)3 * HID * HID;
    unsigned short* wgT   = whh   + (size_t)3 * HID * HID;
    int* deg    = (int*)(wgT + (size_t)3 * HID * HID);
    int* cursor = deg + Nn;
    int* off    = cursor + Nn;
    int* csr    = off + Nn + 1;

    size_t ush = (size_t)Nn * (EMB + 4 * HID) + (size_t)HID * EMB + (size_t)9 * HID * HID;
    size_t needed = ush * 2 + (size_t)(3 * Nn + 1 + E) * sizeof(int);
    if (ws_size < needed) return;

    // CSR by destination
    hipMemsetAsync(deg, 0, sizeof(int) * (size_t)(2 * Nn), stream);
    k_deg <<<(E + 255) / 256, 256, 0, stream>>>(edst, E, deg);
    k_scan<<<1, 1024, 0, stream>>>(deg, Nn, off);
    k_fill<<<(E + 255) / 256, 256, 0, stream>>>(esrc, edst, E, off, cursor, csr);

    // weight casts
    k_cast <<<(HID * EMB + 255) / 256, 256, 0, stream>>>(Wproj, wproj, HID * EMB);
    k_cast <<<(3 * HID * HID + 255) / 256, 256, 0, stream>>>(Wih, wih, 3 * HID * HID);
    k_cast <<<(3 * HID * HID + 255) / 256, 256, 0, stream>>>(Whh, whh, 3 * HID * HID);
    k_castT<<<(3 * HID * HID + 255) / 256, 256, 0, stream>>>(Wg, wgT, 3);
    k_gather_cast<<<(Nn * EMB + 255) / 256, 256, 0, stream>>>(embed, x_lex, x0, Nn, EMB);

    int mb = (Nn + 127) / 128;

    // h0 = x0 @ wproj^T   (K = EMB)
    k_mmS<<<dim3(mb, HID / 128), 256, 0, stream>>>(x0, wproj, hA, Nn, HID, EMB);

    unsigned short* hc = hA;
    unsigned short* hn = hB;
    for (int lay = 0; lay < 3; lay++){
        // aggh = segment_sum(h[src] -> dst)
        k_agg<<<(Nn + 3) / 4, 256, 0, stream>>>(hc, off, csr, aggh, Nn);
        // msg = aggh @ Wg  (wgT is [n][k])
        k_mmS<<<dim3(mb, HID / 128), 256, 0, stream>>>(
            aggh, wgT + (size_t)lay * HID * HID, msgb, Nn, HID, HID);
        // fused GRU: h_next
        k_gru<<<dim3(mb, HID / 64), 256, 0, stream>>>(
            msgb, hc, wih, whh, bih, bhh, hn, Nn);
        unsigned short* t = hc; hc = hn; hn = t;
    }

    k_pool_mlp<<<G, HID, 0, stream>>>(hc, batch, Nn, G, W1, b1, W2, b2, (float*)d_out);
}

// Round 5
// 808.597 us; speedup vs baseline: 3.5571x; 1.0585x over previous
//
#include <hip/hip_runtime.h>
#include <math.h>

constexpr int HID = 256;

typedef __attribute__((ext_vector_type(8))) short bf16x8;
typedef __attribute__((ext_vector_type(4))) float f32x4;

__device__ __forceinline__ float bf2f(unsigned short u){
    union { unsigned int i; float f; } v; v.i = ((unsigned int)u) << 16; return v.f;
}
__device__ __forceinline__ unsigned short f2bf(float f){
    union { float f; unsigned int i; } v; v.f = f;
    return (unsigned short)((v.i + 0x7fffu + ((v.i >> 16) & 1u)) >> 16);
}
__device__ __forceinline__ float sigm(float x){ return 1.f / (1.f + __expf(-x)); }

// async global->LDS, 16B per lane. LDS dest is wave-uniform base; HW adds lane*16.
__device__ __forceinline__ void gll16(const unsigned short* g, unsigned short* l){
    __builtin_amdgcn_global_load_lds(
        (const __attribute__((address_space(1))) void*)g,
        (__attribute__((address_space(3))) void*)l, 16, 0, 0);
}

// ---------------- casts ----------------
__global__ void k_cast(const float* __restrict__ in, unsigned short* __restrict__ out, int n){
    int i = blockIdx.x*blockDim.x + threadIdx.x;
    if (i < n) out[i] = f2bf(in[i]);
}
__global__ void k_gather_cast(const float* __restrict__ embed, const int* __restrict__ idx,
                              unsigned short* __restrict__ x0, int Nn, int EMB){
    int i = blockIdx.x*blockDim.x + threadIdx.x;
    if (i < Nn*EMB){
        int row = i / EMB, k = i % EMB;
        x0[i] = f2bf(embed[(size_t)idx[row]*EMB + k]);
    }
}

// ---------------- CSR build ----------------
__global__ void k_deg(const int* __restrict__ dst, int E, int* __restrict__ deg){
    int i = blockIdx.x*blockDim.x + threadIdx.x;
    if (i < E) atomicAdd(&deg[dst[i]], 1);
}

__global__ void k_scan(const int* __restrict__ deg, int N, int* __restrict__ off){
    __shared__ int part[1024];
    int t = threadIdx.x;
    int chunk = (N + 1023) / 1024;
    int s = t * chunk, e = min(s + chunk, N);
    int sum = 0;
    for (int i = s; i < e; i++) sum += deg[i];
    part[t] = sum;
    __syncthreads();
    for (int o = 1; o < 1024; o <<= 1){
        int v = (t >= o) ? part[t - o] : 0;
        __syncthreads();
        part[t] += v;
        __syncthreads();
    }
    int base = (t == 0) ? 0 : part[t - 1];
    for (int i = s; i < e; i++){ off[i] = base; base += deg[i]; }
    if (e == N && s <= N) off[N] = base;
}

__global__ void k_fill(const int* __restrict__ src, const int* __restrict__ dst, int E,
                       const int* __restrict__ off, int* __restrict__ cursor,
                       int* __restrict__ csr_src){
    int i = blockIdx.x*blockDim.x + threadIdx.x;
    if (i < E){
        int d = dst[i];
        int p = off[d] + atomicAdd(&cursor[d], 1);
        csr_src[p] = src[i];
    }
}

// ---------------- aggregation (bf16 in/out, fp32 acc) ----------------
__global__ void k_agg(const unsigned short* __restrict__ h, const int* __restrict__ off,
                      const int* __restrict__ csr, unsigned short* __restrict__ out, int N){
    int wave = threadIdx.x >> 6, lane = threadIdx.x & 63;
    int d = blockIdx.x * 4 + wave;
    if (d >= N) return;
    int c = lane * 4;
    float a0 = 0.f, a1 = 0.f, a2 = 0.f, a3 = 0.f;
    int s0 = off[d], s1 = off[d + 1];
    int j = s0;
    for (; j + 1 < s1; j += 2){
        int sA = csr[j], sB = csr[j + 1];
        ushort4 vA = *(const ushort4*)(h + (size_t)sA * HID + c);
        ushort4 vB = *(const ushort4*)(h + (size_t)sB * HID + c);
        a0 += bf2f(vA.x) + bf2f(vB.x);
        a1 += bf2f(vA.y) + bf2f(vB.y);
        a2 += bf2f(vA.z) + bf2f(vB.z);
        a3 += bf2f(vA.w) + bf2f(vB.w);
    }
    if (j < s1){
        int sA = csr[j];
        ushort4 vA = *(const ushort4*)(h + (size_t)sA * HID + c);
        a0 += bf2f(vA.x); a1 += bf2f(vA.y); a2 += bf2f(vA.z); a3 += bf2f(vA.w);
    }
    ushort4 o; o.x = f2bf(a0); o.y = f2bf(a1); o.z = f2bf(a2); o.w = f2bf(a3);
    *(ushort4*)(out + (size_t)d * HID + c) = o;
}

// ---------------- single-source GEMM: C = A @ B^T, B is [N][K] row-major, bf16 ----------------
// BM=128, BN=128, BK=32; counted-vmcnt 2-buffer pipeline (loads never drained to 0 mid-loop).
__global__ __launch_bounds__(256, 3) void k_mmS(
    const unsigned short* __restrict__ A, const unsigned short* __restrict__ B,
    unsigned short* __restrict__ C, int M, int N, int K)
{
    __shared__ __align__(16) unsigned short sm[2 * 1024 * 8];
    const int tid = threadIdx.x, w = tid >> 6, l = tid & 63;
    const int wm = w >> 1, wn = w & 1, lr = l & 15, lk = l >> 4;
    const int nby = N >> 7;
    const long row0 = (long)(blockIdx.x / nby) * 128;
    const int  col0 = (blockIdx.x % nby) * 128;

    const unsigned short* ap[2];
    const unsigned short* bp[2];
    #pragma unroll
    for (int s = 0; s < 2; s++){
        int c = s * 256 + tid, row = c >> 2, ks = c & 3;
        long ga = row0 + row; if (ga > M - 1) ga = M - 1;
        int sw = ks ^ ((row >> 1) & 3);
        ap[s] = A + ga * (long)K + sw * 8;
        bp[s] = B + (long)(col0 + row) * K + sw * 8;
    }

    const int NT = K >> 5;
    // prologue: t=0 -> buf0, t=1 -> buf1   (8 loads/wave outstanding)
    #pragma unroll
    for (int s = 0; s < 2; s++){
        gll16(ap[s], sm + (s * 256 + w * 64) * 8);
        gll16(bp[s], sm + (512 + s * 256 + w * 64) * 8);
    }
    #pragma unroll
    for (int s = 0; s < 2; s++){
        gll16(ap[s] + 32, sm + (1024 + s * 256 + w * 64) * 8);
        gll16(bp[s] + 32, sm + (1024 + 512 + s * 256 + w * 64) * 8);
    }

    f32x4 acc[4][4] = {};
    for (int t = 0; t < NT; t++){
        const int cur = t & 1;
        if (t < NT - 1) asm volatile("s_waitcnt vmcnt(4)" ::: "memory");
        else            asm volatile("s_waitcnt vmcnt(0)" ::: "memory");
        __builtin_amdgcn_s_barrier();

        const unsigned short* As = sm + cur * 8192;
        const unsigned short* Bs = As + 4096;
        bf16x8 af[4], bfb[4];
        #pragma unroll
        for (int i = 0; i < 4; i++){
            int ra = wm * 64 + i * 16 + lr;
            af[i]  = *(const bf16x8*)(As + (ra * 4 + (lk ^ ((ra >> 1) & 3))) * 8);
            int rb = wn * 64 + i * 16 + lr;
            bfb[i] = *(const bf16x8*)(Bs + (rb * 4 + (lk ^ ((rb >> 1) & 3))) * 8);
        }
        asm volatile("s_waitcnt lgkmcnt(0)" ::: "memory");
        __builtin_amdgcn_s_barrier();

        if (t + 2 < NT){
            const int k0 = (t + 2) * 32;
            #pragma unroll
            for (int s = 0; s < 2; s++){
                gll16(ap[s] + k0, sm + (cur * 1024 + s * 256 + w * 64) * 8);
                gll16(bp[s] + k0, sm + (cur * 1024 + 512 + s * 256 + w * 64) * 8);
            }
        }
        #pragma unroll
        for (int mi = 0; mi < 4; mi++)
            #pragma unroll
            for (int ni = 0; ni < 4; ni++)
                acc[mi][ni] = __builtin_amdgcn_mfma_f32_16x16x32_bf16(af[mi], bfb[ni], acc[mi][ni], 0, 0, 0);
    }

    #pragma unroll
    for (int mi = 0; mi < 4; mi++)
        #pragma unroll
        for (int ni = 0; ni < 4; ni++)
            #pragma unroll
            for (int r = 0; r < 4; r++){
                long row = row0 + wm * 64 + mi * 16 + lk * 4 + r;
                if (row < M){
                    int col = col0 + wn * 64 + ni * 16 + lr;
                    C[row * (long)N + col] = f2bf(acc[mi][ni][r]);
                }
            }
}

// ---------------- fused GRU with pre-composed input weights ----------------
// WIH here = Weff = W_ih @ Wg^T, so gates read AGG (pre-message h-sum) directly:
//   accR = AGG@Weff_r^T + H@Whh_r^T ; accZ likewise ; accI = AGG@Weff_n^T ; accHn = H@Whh_n^T
// 128x64 out-slice, 4 waves (2x2), wave tile 64x32 per set, K=256, BK=32, counted-vmcnt dbuf.
__global__ __launch_bounds__(256, 2) void k_gru(
    const unsigned short* __restrict__ AGG, const unsigned short* __restrict__ H,
    const unsigned short* __restrict__ WIH, const unsigned short* __restrict__ WHH,
    const float* __restrict__ bih, const float* __restrict__ bhh,
    unsigned short* __restrict__ HN, int M)
{
    constexpr int K = HID;
    __shared__ __align__(16) unsigned short sm[2 * 2560 * 8];  // 80 KiB
    const int tid = threadIdx.x, w = tid >> 6, l = tid & 63;
    const int wm = w >> 1, wn = w & 1, lr = l & 15, lk = l >> 4;
    const long row0 = (long)(blockIdx.x >> 2) * 128;
    const int  c0 = (blockIdx.x & 3) * 64;

    const unsigned short* a1p[2];
    const unsigned short* a2p[2];
    const unsigned short* bp[6];
    #pragma unroll
    for (int s = 0; s < 2; s++){
        int c = s * 256 + tid, row = c >> 2, ks = c & 3;
        long ga = row0 + row; if (ga > M - 1) ga = M - 1;
        long o = ga * (long)K + (ks ^ ((row >> 1) & 3)) * 8;
        a1p[s] = AGG + o;
        a2p[s] = H + o;
    }
    {
        int r = tid >> 2, ks = tid & 3;
        int sw = (ks ^ ((r >> 1) & 3)) * 8;
        #pragma unroll
        for (int j = 0; j < 6; j++){
            int gate = (j < 3) ? j : j - 3;
            const unsigned short* W = (j < 3) ? WIH : WHH;
            bp[j] = W + (long)(gate * HID + c0 + r) * K + sw;
        }
    }

    // prologue: t=0 -> buf0, t=1 -> buf1  (20 loads/wave outstanding)
    #pragma unroll
    for (int b = 0; b < 2; b++){
        const int k0 = b * 32;
        #pragma unroll
        for (int s = 0; s < 2; s++){
            gll16(a1p[s] + k0, sm + (b * 2560 + s * 256 + w * 64) * 8);
            gll16(a2p[s] + k0, sm + (b * 2560 + 512 + s * 256 + w * 64) * 8);
        }
        #pragma unroll
        for (int j = 0; j < 6; j++)
            gll16(bp[j] + k0, sm + (b * 2560 + 1024 + j * 256 + w * 64) * 8);
    }

    f32x4 aR[4][2] = {}, aZ[4][2] = {}, aI[4][2] = {}, aHn[4][2] = {};

    for (int t = 0; t < 8; t++){
        const int cur = t & 1;
        if (t < 7) asm volatile("s_waitcnt vmcnt(10)" ::: "memory");
        else       asm volatile("s_waitcnt vmcnt(0)" ::: "memory");
        __builtin_amdgcn_s_barrier();

        const unsigned short* As1 = sm + cur * 20480;
        const unsigned short* As2 = As1 + 4096;
        const unsigned short* Bs  = As1 + 8192;

        bf16x8 a1[4], a2[4], bb[6][2];
        #pragma unroll
        for (int i = 0; i < 4; i++){
            int ra = wm * 64 + i * 16 + lr;
            int sa = (ra * 4 + (lk ^ ((ra >> 1) & 3))) * 8;
            a1[i] = *(const bf16x8*)(As1 + sa);
            a2[i] = *(const bf16x8*)(As2 + sa);
        }
        #pragma unroll
        for (int ni = 0; ni < 2; ni++){
            int rb = wn * 32 + ni * 16 + lr;
            int sb = (rb * 4 + (lk ^ ((rb >> 1) & 3))) * 8;
            #pragma unroll
            for (int j = 0; j < 6; j++)
                bb[j][ni] = *(const bf16x8*)(Bs + j * 2048 + sb);
        }
        asm volatile("s_waitcnt lgkmcnt(0)" ::: "memory");
        __builtin_amdgcn_s_barrier();

        if (t + 2 < 8){
            const int k0 = (t + 2) * 32;
            #pragma unroll
            for (int s = 0; s < 2; s++){
                gll16(a1p[s] + k0, sm + (cur * 2560 + s * 256 + w * 64) * 8);
                gll16(a2p[s] + k0, sm + (cur * 2560 + 512 + s * 256 + w * 64) * 8);
            }
            #pragma unroll
            for (int j = 0; j < 6; j++)
                gll16(bp[j] + k0, sm + (cur * 2560 + 1024 + j * 256 + w * 64) * 8);
        }

        #pragma unroll
        for (int ni = 0; ni < 2; ni++)
            #pragma unroll
            for (int mi = 0; mi < 4; mi++){
                aR[mi][ni]  = __builtin_amdgcn_mfma_f32_16x16x32_bf16(a1[mi], bb[0][ni], aR[mi][ni], 0, 0, 0);
                aR[mi][ni]  = __builtin_amdgcn_mfma_f32_16x16x32_bf16(a2[mi], bb[3][ni], aR[mi][ni], 0, 0, 0);
                aZ[mi][ni]  = __builtin_amdgcn_mfma_f32_16x16x32_bf16(a1[mi], bb[1][ni], aZ[mi][ni], 0, 0, 0);
                aZ[mi][ni]  = __builtin_amdgcn_mfma_f32_16x16x32_bf16(a2[mi], bb[4][ni], aZ[mi][ni], 0, 0, 0);
                aI[mi][ni]  = __builtin_amdgcn_mfma_f32_16x16x32_bf16(a1[mi], bb[2][ni], aI[mi][ni], 0, 0, 0);
                aHn[mi][ni] = __builtin_amdgcn_mfma_f32_16x16x32_bf16(a2[mi], bb[5][ni], aHn[mi][ni], 0, 0, 0);
            }
    }

    #pragma unroll
    for (int ni = 0; ni < 2; ni++){
        int gc = c0 + wn * 32 + ni * 16 + lr;
        float br  = bih[gc] + bhh[gc];
        float bz  = bih[HID + gc] + bhh[HID + gc];
        float bin = bih[2 * HID + gc];
        float bhn = bhh[2 * HID + gc];
        #pragma unroll
        for (int mi = 0; mi < 4; mi++)
            #pragma unroll
            for (int r = 0; r < 4; r++){
                long row = row0 + wm * 64 + mi * 16 + lk * 4 + r;
                if (row < M){
                    float rr = sigm(aR[mi][ni][r] + br);
                    float zz = sigm(aZ[mi][ni][r] + bz);
                    float nn = tanhf(aI[mi][ni][r] + bin + rr * (aHn[mi][ni][r] + bhn));
                    float hv = bf2f(H[row * HID + gc]);
                    HN[row * HID + gc] = f2bf((1.f - zz) * nn + zz * hv);
                }
            }
    }
}

// ---------------- pool (segment max over sorted batch) + MLP head ----------------
__global__ void k_pool_mlp(const unsigned short* __restrict__ h, const int* __restrict__ batch,
                           int Nn, int G,
                           const float* __restrict__ W1, const float* __restrict__ b1,
                           const float* __restrict__ W2, const float* __restrict__ b2,
                           float* __restrict__ out){
    int g = blockIdx.x;
    __shared__ float pool[HID];
    __shared__ float hid[64];

    int lo = 0, hi = Nn;
    while (lo < hi){ int mid = (lo + hi) >> 1; if (batch[mid] < g) lo = mid + 1; else hi = mid; }
    int s = lo;
    lo = s; hi = Nn;
    while (lo < hi){ int mid = (lo + hi) >> 1; if (batch[mid] < g + 1) lo = mid + 1; else hi = mid; }
    int e = lo;

    int c = threadIdx.x;
    float mx = -INFINITY;
    for (int i = s; i < e; i++) mx = fmaxf(mx, bf2f(h[(size_t)i * HID + c]));
    pool[c] = mx;
    out[(size_t)G + (size_t)g * HID + c] = mx;
    __syncthreads();

    if (c < 64){
        float sacc = b1[c];
        for (int k = 0; k < HID; k++) sacc += pool[k] * W1[c * HID + k];
        hid[c] = fmaxf(sacc, 0.f) * W2[c];
    }
    __syncthreads();
    if (c == 0){
        float sacc = b2[0];
        for (int j = 0; j < 64; j++) sacc += hid[j];
        out[g] = sacc;
    }
}

extern "C" void kernel_launch(void* const* d_in, const int* in_sizes, int n_in,
                              void* d_out, int out_size, void* d_ws, size_t ws_size,
                              hipStream_t stream){
    const int*   x_lex = (const int*)d_in[0];
    const int*   edge  = (const int*)d_in[1];
    const int*   batch = (const int*)d_in[2];
    const float* embed = (const float*)d_in[3];
    const float* Wproj = (const float*)d_in[4];
    const float* Wg    = (const float*)d_in[5];
    const float* Wih   = (const float*)d_in[6];
    const float* bih   = (const float*)d_in[7];
    const float* Whh   = (const float*)d_in[8];
    const float* bhh   = (const float*)d_in[9];
    const float* W1    = (const float*)d_in[10];
    const float* b1    = (const float*)d_in[11];
    const float* W2    = (const float*)d_in[12];
    const float* b2    = (const float*)d_in[13];

    int Nn  = in_sizes[0];
    int E   = in_sizes[1] / 2;
    int G   = out_size / (1 + HID);
    int EMB = in_sizes[4] / HID;   // W_proj is [HID, EMBED]

    const int* esrc = edge;
    const int* edst = edge + E;

    size_t HH = (size_t)HID * HID;
    unsigned short* x0    = (unsigned short*)d_ws;
    unsigned short* hA    = x0    + (size_t)Nn * EMB;
    unsigned short* hB    = hA    + (size_t)Nn * HID;
    unsigned short* aggh  = hB    + (size_t)Nn * HID;
    unsigned short* wproj = aggh  + (size_t)Nn * HID;
    unsigned short* wih   = wproj + (size_t)HID * EMB;
    unsigned short* whh   = wih   + 3 * HH;
    unsigned short* wg    = whh   + 3 * HH;   // Wg in NATURAL [k? no: [j][n]] row-major layout
    unsigned short* weff  = wg    + 3 * HH;   // 3 layers x [768][256]
    int* deg    = (int*)(weff + 9 * HH);
    int* cursor = deg + Nn;
    int* off    = cursor + Nn;
    int* csr    = off + Nn + 1;

    size_t ush = (size_t)Nn * (EMB + 3 * HID) + (size_t)HID * EMB + 18 * HH;
    size_t needed = ush * 2 + (size_t)(3 * Nn + 1 + E) * sizeof(int);
    if (ws_size < needed) return;

    // CSR by destination
    hipMemsetAsync(deg, 0, sizeof(int) * (size_t)(2 * Nn), stream);
    k_deg <<<(E + 255) / 256, 256, 0, stream>>>(edst, E, deg);
    k_scan<<<1, 1024, 0, stream>>>(deg, Nn, off);
    k_fill<<<(E + 255) / 256, 256, 0, stream>>>(esrc, edst, E, off, cursor, csr);

    // weight casts
    k_cast <<<(HID * EMB + 255) / 256, 256, 0, stream>>>(Wproj, wproj, HID * EMB);
    k_cast <<<(int)(3 * HH + 255) / 256, 256, 0, stream>>>(Wih, wih, 3 * HH);
    k_cast <<<(int)(3 * HH + 255) / 256, 256, 0, stream>>>(Whh, whh, 3 * HH);
    k_cast <<<(int)(3 * HH + 255) / 256, 256, 0, stream>>>(Wg, wg, 3 * HH);   // natural layout
    k_gather_cast<<<(Nn * EMB + 255) / 256, 256, 0, stream>>>(embed, x_lex, x0, Nn, EMB);

    // Weff_l[m][j] = sum_n Wih[m][n] * Wg_l[j][n]  =  (W_ih @ Wg_l^T)[m][j]
    // k_mmS computes C[m][j] = sum_n A[m][n]*B[j][n] with B row-major [j][n] -> B = Wg natural.
    for (int lay = 0; lay < 3; lay++)
        k_mmS<<<6 * 2, 256, 0, stream>>>(wih, wg + lay * HH, weff + lay * 3 * HH,
                                         3 * HID, HID, HID);

    int mb = (Nn + 127) / 128;

    // h0 = x0 @ wproj^T
    k_mmS<<<mb * 2, 256, 0, stream>>>(x0, wproj, hA, Nn, HID, EMB);

    unsigned short* hc = hA;
    unsigned short* hn = hB;
    for (int lay = 0; lay < 3; lay++){
        k_agg<<<(Nn + 3) / 4, 256, 0, stream>>>(hc, off, csr, aggh, Nn);
        k_gru<<<mb * 4, 256, 0, stream>>>(
            aggh, hc, weff + lay * 3 * HH, whh, bih, bhh, hn, Nn);
        unsigned short* t = hc; hc = hn; hn = t;
    }

    k_pool_mlp<<<G, HID, 0, stream>>>(hc, batch, Nn, G, W1, b1, W2, b2, (float*)d_out);
}

// Round 6
// 682.532 us; speedup vs baseline: 4.2141x; 1.1847x over previous
//
#include <hip/hip_runtime.h>
#include <math.h>

constexpr int HID = 256;

typedef __attribute__((ext_vector_type(8))) short bf16x8;
typedef __attribute__((ext_vector_type(4))) float f32x4;

__device__ __forceinline__ float bf2f(unsigned short u){
    union { unsigned int i; float f; } v; v.i = ((unsigned int)u) << 16; return v.f;
}
__device__ __forceinline__ unsigned short f2bf(float f){
    union { float f; unsigned int i; } v; v.f = f;
    return (unsigned short)((v.i + 0x7fffu + ((v.i >> 16) & 1u)) >> 16);
}
__device__ __forceinline__ float sigm(float x){ return 1.f / (1.f + __expf(-x)); }

// bijective XCD-chunked swizzle (m204): consecutive ORIG ids land on the same XCD.
__device__ __forceinline__ int xcd_chunk(int bid, int nwg){
    int q = nwg >> 3, r = nwg & 7;
    int xcd = bid & 7, pos = bid >> 3;
    return (xcd < r) ? xcd * (q + 1) + pos : r * (q + 1) + (xcd - r) * q + pos;
}

// async global->LDS, 16B per lane. LDS dest is wave-uniform base; HW adds lane*16.
__device__ __forceinline__ void gll16(const unsigned short* g, unsigned short* l){
    __builtin_amdgcn_global_load_lds(
        (const __attribute__((address_space(1))) void*)g,
        (__attribute__((address_space(3))) void*)l, 16, 0, 0);
}

// ---------------- merged weight casts + embedding gather ----------------
__global__ void k_prep(const float* __restrict__ Wproj, const float* __restrict__ Wih,
                       const float* __restrict__ Whh, const float* __restrict__ Wg,
                       const float* __restrict__ embed, const int* __restrict__ idx,
                       unsigned short* __restrict__ wproj, unsigned short* __restrict__ wih,
                       unsigned short* __restrict__ whh, unsigned short* __restrict__ wg,
                       unsigned short* __restrict__ x0, int Nn, int EMB){
    const long n1 = (long)HID * EMB, n2 = 3L * HID * HID;
    const long n5 = (long)Nn * EMB;
    const long tot = n1 + 3 * n2 + n5;
    for (long i = blockIdx.x * (long)blockDim.x + threadIdx.x; i < tot;
         i += (long)gridDim.x * blockDim.x){
        long j = i;
        if (j < n1){ wproj[j] = f2bf(Wproj[j]); continue; }
        j -= n1;
        if (j < n2){ wih[j] = f2bf(Wih[j]); continue; }
        j -= n2;
        if (j < n2){ whh[j] = f2bf(Whh[j]); continue; }
        j -= n2;
        if (j < n2){ wg[j] = f2bf(Wg[j]); continue; }
        j -= n2;
        int row = (int)(j / EMB), k = (int)(j % EMB);
        x0[j] = f2bf(embed[(size_t)idx[row] * EMB + k]);
    }
}

// ---------------- CSR build ----------------
__global__ void k_deg(const int* __restrict__ dst, int E, int* __restrict__ deg){
    int i = blockIdx.x*blockDim.x + threadIdx.x;
    if (i < E) atomicAdd(&deg[dst[i]], 1);
}

__global__ void k_scan(const int* __restrict__ deg, int N, int* __restrict__ off){
    __shared__ int part[1024];
    int t = threadIdx.x;
    int chunk = (N + 1023) / 1024;
    int s = t * chunk, e = min(s + chunk, N);
    int sum = 0;
    for (int i = s; i < e; i++) sum += deg[i];
    part[t] = sum;
    __syncthreads();
    for (int o = 1; o < 1024; o <<= 1){
        int v = (t >= o) ? part[t - o] : 0;
        __syncthreads();
        part[t] += v;
        __syncthreads();
    }
    int base = (t == 0) ? 0 : part[t - 1];
    for (int i = s; i < e; i++){ off[i] = base; base += deg[i]; }
    if (e == N && s <= N) off[N] = base;
}

__global__ void k_fill(const int* __restrict__ src, const int* __restrict__ dst, int E,
                       const int* __restrict__ off, int* __restrict__ cursor,
                       int* __restrict__ csr_src){
    int i = blockIdx.x*blockDim.x + threadIdx.x;
    if (i < E){
        int d = dst[i];
        int p = off[d] + atomicAdd(&cursor[d], 1);
        csr_src[p] = src[i];
    }
}

// ---------------- aggregation: 2 rows per wave, 16B/lane ----------------
__global__ void k_agg(const unsigned short* __restrict__ h, const int* __restrict__ off,
                      const int* __restrict__ csr, unsigned short* __restrict__ out, int N){
    int wave = threadIdx.x >> 6, lane = threadIdx.x & 63;
    int d = blockIdx.x * 8 + wave * 2 + (lane >> 5);
    if (d >= N) return;
    int c = (lane & 31) * 8;
    float a[8] = {};
    int s0 = off[d], s1 = off[d + 1];
    int j = s0;
    for (; j + 1 < s1; j += 2){
        int sA = csr[j], sB = csr[j + 1];
        bf16x8 vA = *(const bf16x8*)(h + (size_t)sA * HID + c);
        bf16x8 vB = *(const bf16x8*)(h + (size_t)sB * HID + c);
        #pragma unroll
        for (int q = 0; q < 8; q++)
            a[q] += bf2f((unsigned short)vA[q]) + bf2f((unsigned short)vB[q]);
    }
    if (j < s1){
        bf16x8 vA = *(const bf16x8*)(h + (size_t)csr[j] * HID + c);
        #pragma unroll
        for (int q = 0; q < 8; q++) a[q] += bf2f((unsigned short)vA[q]);
    }
    bf16x8 o;
    #pragma unroll
    for (int q = 0; q < 8; q++) o[q] = (short)f2bf(a[q]);
    *(bf16x8*)(out + (size_t)d * HID + c) = o;
}

// ---------------- single-source GEMM: C = A @ B^T, B is [N][K] row-major, bf16 ----------------
// BM=128, BN=128, BK=32; counted-vmcnt 2-buffer pipeline; XCD-chunked block swizzle.
// Optional layer batching: layer = orig / nbx, B += layer*lsB, C += layer*lsC.
__global__ __launch_bounds__(256, 3) void k_mmS(
    const unsigned short* __restrict__ A, const unsigned short* __restrict__ B,
    unsigned short* __restrict__ C, int M, int N, int K,
    int nbx, long lsB, long lsC)
{
    __shared__ __align__(16) unsigned short sm[2 * 1024 * 8];
    const int tid = threadIdx.x, w = tid >> 6, l = tid & 63;
    const int wm = w >> 1, wn = w & 1, lr = l & 15, lk = l >> 4;

    const int orig = xcd_chunk(blockIdx.x, gridDim.x);
    const int layer = orig / nbx, sub = orig % nbx;
    B += layer * lsB;
    C += layer * lsC;
    const int nby = N >> 7;
    const long row0 = (long)(sub / nby) * 128;
    const int  col0 = (sub % nby) * 128;

    const unsigned short* ap[2];
    const unsigned short* bp[2];
    #pragma unroll
    for (int s = 0; s < 2; s++){
        int c = s * 256 + tid, row = c >> 2, ks = c & 3;
        long ga = row0 + row; if (ga > M - 1) ga = M - 1;
        int sw = ks ^ ((row >> 1) & 3);
        ap[s] = A + ga * (long)K + sw * 8;
        bp[s] = B + (long)(col0 + row) * K + sw * 8;
    }

    const int NT = K >> 5;
    #pragma unroll
    for (int s = 0; s < 2; s++){
        gll16(ap[s], sm + (s * 256 + w * 64) * 8);
        gll16(bp[s], sm + (512 + s * 256 + w * 64) * 8);
    }
    #pragma unroll
    for (int s = 0; s < 2; s++){
        gll16(ap[s] + 32, sm + (1024 + s * 256 + w * 64) * 8);
        gll16(bp[s] + 32, sm + (1024 + 512 + s * 256 + w * 64) * 8);
    }

    f32x4 acc[4][4] = {};
    for (int t = 0; t < NT; t++){
        const int cur = t & 1;
        if (t < NT - 1) asm volatile("s_waitcnt vmcnt(4)" ::: "memory");
        else            asm volatile("s_waitcnt vmcnt(0)" ::: "memory");
        __builtin_amdgcn_s_barrier();

        const unsigned short* As = sm + cur * 8192;
        const unsigned short* Bs = As + 4096;
        bf16x8 af[4], bfb[4];
        #pragma unroll
        for (int i = 0; i < 4; i++){
            int ra = wm * 64 + i * 16 + lr;
            af[i]  = *(const bf16x8*)(As + (ra * 4 + (lk ^ ((ra >> 1) & 3))) * 8);
            int rb = wn * 64 + i * 16 + lr;
            bfb[i] = *(const bf16x8*)(Bs + (rb * 4 + (lk ^ ((rb >> 1) & 3))) * 8);
        }
        asm volatile("s_waitcnt lgkmcnt(0)" ::: "memory");
        __builtin_amdgcn_s_barrier();

        if (t + 2 < NT){
            const int k0 = (t + 2) * 32;
            #pragma unroll
            for (int s = 0; s < 2; s++){
                gll16(ap[s] + k0, sm + (cur * 1024 + s * 256 + w * 64) * 8);
                gll16(bp[s] + k0, sm + (cur * 1024 + 512 + s * 256 + w * 64) * 8);
            }
        }
        #pragma unroll
        for (int mi = 0; mi < 4; mi++)
            #pragma unroll
            for (int ni = 0; ni < 4; ni++)
                acc[mi][ni] = __builtin_amdgcn_mfma_f32_16x16x32_bf16(af[mi], bfb[ni], acc[mi][ni], 0, 0, 0);
    }

    #pragma unroll
    for (int mi = 0; mi < 4; mi++)
        #pragma unroll
        for (int ni = 0; ni < 4; ni++)
            #pragma unroll
            for (int r = 0; r < 4; r++){
                long row = row0 + wm * 64 + mi * 16 + lk * 4 + r;
                if (row < M){
                    int col = col0 + wn * 64 + ni * 16 + lr;
                    C[row * (long)N + col] = f2bf(acc[mi][ni][r]);
                }
            }
}

// ---------------- fused GRU with pre-composed input weights ----------------
// WIH = Weff = W_ih @ Wg^T; gates read AGG directly.
// 128x64 out-slice, 4 waves, wave tile 64x32 per gate-set, K=256, BK=32, counted-vmcnt dbuf.
// XCD-chunked swizzle: the 4 col-slices of one row-block co-locate on one XCD (A L2-shared).
__global__ __launch_bounds__(256, 2) void k_gru(
    const unsigned short* __restrict__ AGG, const unsigned short* __restrict__ H,
    const unsigned short* __restrict__ WIH, const unsigned short* __restrict__ WHH,
    const float* __restrict__ bih, const float* __restrict__ bhh,
    unsigned short* __restrict__ HN, int M)
{
    constexpr int K = HID;
    __shared__ __align__(16) unsigned short sm[2 * 2560 * 8];  // 80 KiB
    const int tid = threadIdx.x, w = tid >> 6, l = tid & 63;
    const int wm = w >> 1, wn = w & 1, lr = l & 15, lk = l >> 4;
    const int orig = xcd_chunk(blockIdx.x, gridDim.x);
    const long row0 = (long)(orig >> 2) * 128;
    const int  c0 = (orig & 3) * 64;

    const unsigned short* a1p[2];
    const unsigned short* a2p[2];
    const unsigned short* bp[6];
    #pragma unroll
    for (int s = 0; s < 2; s++){
        int c = s * 256 + tid, row = c >> 2, ks = c & 3;
        long ga = row0 + row; if (ga > M - 1) ga = M - 1;
        long o = ga * (long)K + (ks ^ ((row >> 1) & 3)) * 8;
        a1p[s] = AGG + o;
        a2p[s] = H + o;
    }
    {
        int r = tid >> 2, ks = tid & 3;
        int sw = (ks ^ ((r >> 1) & 3)) * 8;
        #pragma unroll
        for (int j = 0; j < 6; j++){
            int gate = (j < 3) ? j : j - 3;
            const unsigned short* W = (j < 3) ? WIH : WHH;
            bp[j] = W + (long)(gate * HID + c0 + r) * K + sw;
        }
    }

    // prologue: t=0 -> buf0, t=1 -> buf1  (20 loads/wave outstanding)
    #pragma unroll
    for (int b = 0; b < 2; b++){
        const int k0 = b * 32;
        #pragma unroll
        for (int s = 0; s < 2; s++){
            gll16(a1p[s] + k0, sm + (b * 2560 + s * 256 + w * 64) * 8);
            gll16(a2p[s] + k0, sm + (b * 2560 + 512 + s * 256 + w * 64) * 8);
        }
        #pragma unroll
        for (int j = 0; j < 6; j++)
            gll16(bp[j] + k0, sm + (b * 2560 + 1024 + j * 256 + w * 64) * 8);
    }

    f32x4 aR[4][2] = {}, aZ[4][2] = {}, aI[4][2] = {}, aHn[4][2] = {};

    for (int t = 0; t < 8; t++){
        const int cur = t & 1;
        if (t < 7) asm volatile("s_waitcnt vmcnt(10)" ::: "memory");
        else       asm volatile("s_waitcnt vmcnt(0)" ::: "memory");
        __builtin_amdgcn_s_barrier();

        const unsigned short* As1 = sm + cur * 20480;
        const unsigned short* As2 = As1 + 4096;
        const unsigned short* Bs  = As1 + 8192;

        bf16x8 a1[4], a2[4], bb[6][2];
        #pragma unroll
        for (int i = 0; i < 4; i++){
            int ra = wm * 64 + i * 16 + lr;
            int sa = (ra * 4 + (lk ^ ((ra >> 1) & 3))) * 8;
            a1[i] = *(const bf16x8*)(As1 + sa);
            a2[i] = *(const bf16x8*)(As2 + sa);
        }
        #pragma unroll
        for (int ni = 0; ni < 2; ni++){
            int rb = wn * 32 + ni * 16 + lr;
            int sb = (rb * 4 + (lk ^ ((rb >> 1) & 3))) * 8;
            #pragma unroll
            for (int j = 0; j < 6; j++)
                bb[j][ni] = *(const bf16x8*)(Bs + j * 2048 + sb);
        }
        asm volatile("s_waitcnt lgkmcnt(0)" ::: "memory");
        __builtin_amdgcn_s_barrier();

        if (t + 2 < 8){
            const int k0 = (t + 2) * 32;
            #pragma unroll
            for (int s = 0; s < 2; s++){
                gll16(a1p[s] + k0, sm + (cur * 2560 + s * 256 + w * 64) * 8);
                gll16(a2p[s] + k0, sm + (cur * 2560 + 512 + s * 256 + w * 64) * 8);
            }
            #pragma unroll
            for (int j = 0; j < 6; j++)
                gll16(bp[j] + k0, sm + (cur * 2560 + 1024 + j * 256 + w * 64) * 8);
        }

        #pragma unroll
        for (int ni = 0; ni < 2; ni++)
            #pragma unroll
            for (int mi = 0; mi < 4; mi++){
                aR[mi][ni]  = __builtin_amdgcn_mfma_f32_16x16x32_bf16(a1[mi], bb[0][ni], aR[mi][ni], 0, 0, 0);
                aR[mi][ni]  = __builtin_amdgcn_mfma_f32_16x16x32_bf16(a2[mi], bb[3][ni], aR[mi][ni], 0, 0, 0);
                aZ[mi][ni]  = __builtin_amdgcn_mfma_f32_16x16x32_bf16(a1[mi], bb[1][ni], aZ[mi][ni], 0, 0, 0);
                aZ[mi][ni]  = __builtin_amdgcn_mfma_f32_16x16x32_bf16(a2[mi], bb[4][ni], aZ[mi][ni], 0, 0, 0);
                aI[mi][ni]  = __builtin_amdgcn_mfma_f32_16x16x32_bf16(a1[mi], bb[2][ni], aI[mi][ni], 0, 0, 0);
                aHn[mi][ni] = __builtin_amdgcn_mfma_f32_16x16x32_bf16(a2[mi], bb[5][ni], aHn[mi][ni], 0, 0, 0);
            }
    }

    #pragma unroll
    for (int ni = 0; ni < 2; ni++){
        int gc = c0 + wn * 32 + ni * 16 + lr;
        float br  = bih[gc] + bhh[gc];
        float bz  = bih[HID + gc] + bhh[HID + gc];
        float bin = bih[2 * HID + gc];
        float bhn = bhh[2 * HID + gc];
        #pragma unroll
        for (int mi = 0; mi < 4; mi++)
            #pragma unroll
            for (int r = 0; r < 4; r++){
                long row = row0 + wm * 64 + mi * 16 + lk * 4 + r;
                if (row < M){
                    float rr = sigm(aR[mi][ni][r] + br);
                    float zz = sigm(aZ[mi][ni][r] + bz);
                    float nn = tanhf(aI[mi][ni][r] + bin + rr * (aHn[mi][ni][r] + bhn));
                    float hv = bf2f(H[row * HID + gc]);
                    HN[row * HID + gc] = f2bf((1.f - zz) * nn + zz * hv);
                }
            }
    }
}

// ---------------- pool (segment max over sorted batch) + MLP head ----------------
__global__ void k_pool_mlp(const unsigned short* __restrict__ h, const int* __restrict__ batch,
                           int Nn, int G,
                           const float* __restrict__ W1, const float* __restrict__ b1,
                           const float* __restrict__ W2, const float* __restrict__ b2,
                           float* __restrict__ out){
    int g = blockIdx.x;
    __shared__ float pool[HID];
    __shared__ float hid[64];

    int lo = 0, hi = Nn;
    while (lo < hi){ int mid = (lo + hi) >> 1; if (batch[mid] < g) lo = mid + 1; else hi = mid; }
    int s = lo;
    lo = s; hi = Nn;
    while (lo < hi){ int mid = (lo + hi) >> 1; if (batch[mid] < g + 1) lo = mid + 1; else hi = mid; }
    int e = lo;

    int c = threadIdx.x;
    float mx = -INFINITY;
    for (int i = s; i < e; i++) mx = fmaxf(mx, bf2f(h[(size_t)i * HID + c]));
    pool[c] = mx;
    out[(size_t)G + (size_t)g * HID + c] = mx;
    __syncthreads();

    if (c < 64){
        float sacc = b1[c];
        for (int k = 0; k < HID; k++) sacc += pool[k] * W1[c * HID + k];
        hid[c] = fmaxf(sacc, 0.f) * W2[c];
    }
    __syncthreads();
    if (c == 0){
        float sacc = b2[0];
        for (int j = 0; j < 64; j++) sacc += hid[j];
        out[g] = sacc;
    }
}

extern "C" void kernel_launch(void* const* d_in, const int* in_sizes, int n_in,
                              void* d_out, int out_size, void* d_ws, size_t ws_size,
                              hipStream_t stream){
    const int*   x_lex = (const int*)d_in[0];
    const int*   edge  = (const int*)d_in[1];
    const int*   batch = (const int*)d_in[2];
    const float* embed = (const float*)d_in[3];
    const float* Wproj = (const float*)d_in[4];
    const float* Wg    = (const float*)d_in[5];
    const float* Wih   = (const float*)d_in[6];
    const float* bih   = (const float*)d_in[7];
    const float* Whh   = (const float*)d_in[8];
    const float* bhh   = (const float*)d_in[9];
    const float* W1    = (const float*)d_in[10];
    const float* b1    = (const float*)d_in[11];
    const float* W2    = (const float*)d_in[12];
    const float* b2    = (const float*)d_in[13];

    int Nn  = in_sizes[0];
    int E   = in_sizes[1] / 2;
    int G   = out_size / (1 + HID);
    int EMB = in_sizes[4] / HID;   // W_proj is [HID, EMBED]

    const int* esrc = edge;
    const int* edst = edge + E;

    size_t HH = (size_t)HID * HID;
    unsigned short* x0    = (unsigned short*)d_ws;
    unsigned short* hA    = x0    + (size_t)Nn * EMB;
    unsigned short* hB    = hA    + (size_t)Nn * HID;
    unsigned short* aggh  = hB    + (size_t)Nn * HID;
    unsigned short* wproj = aggh  + (size_t)Nn * HID;
    unsigned short* wih   = wproj + (size_t)HID * EMB;
    unsigned short* whh   = wih   + 3 * HH;
    unsigned short* wg    = whh   + 3 * HH;   // Wg natural row-major [k][n] per layer
    unsigned short* weff  = wg    + 3 * HH;   // 3 layers x [768][256]
    int* deg    = (int*)(weff + 9 * HH);
    int* cursor = deg + Nn;
    int* off    = cursor + Nn;
    int* csr    = off + Nn + 1;

    size_t ush = (size_t)Nn * (EMB + 3 * HID) + (size_t)HID * EMB + 18 * HH;
    size_t needed = ush * 2 + (size_t)(3 * Nn + 1 + E) * sizeof(int);
    if (ws_size < needed) return;

    // CSR by destination
    hipMemsetAsync(deg, 0, sizeof(int) * (size_t)(2 * Nn), stream);
    k_deg <<<(E + 255) / 256, 256, 0, stream>>>(edst, E, deg);
    k_scan<<<1, 1024, 0, stream>>>(deg, Nn, off);
    k_fill<<<(E + 255) / 256, 256, 0, stream>>>(esrc, edst, E, off, cursor, csr);

    // merged weight casts + embed gather
    k_prep<<<2048, 256, 0, stream>>>(Wproj, Wih, Whh, Wg, embed, x_lex,
                                     wproj, wih, whh, wg, x0, Nn, EMB);

    // Weff_l = Wih @ Wg_l^T, all 3 layers in one dispatch (12 blocks/layer)
    k_mmS<<<36, 256, 0, stream>>>(wih, wg, weff, 3 * HID, HID, HID,
                                  12, (long)HH, (long)(3 * HH));

    int mb = (Nn + 127) / 128;

    // h0 = x0 @ wproj^T
    k_mmS<<<mb * 2, 256, 0, stream>>>(x0, wproj, hA, Nn, HID, EMB,
                                      mb * 2, 0L, 0L);

    unsigned short* hc = hA;
    unsigned short* hn = hB;
    for (int lay = 0; lay < 3; lay++){
        k_agg<<<(Nn + 7) / 8, 256, 0, stream>>>(hc, off, csr, aggh, Nn);
        k_gru<<<mb * 4, 256, 0, stream>>>(
            aggh, hc, weff + (size_t)lay * 3 * HH, whh, bih, bhh, hn, Nn);
        unsigned short* t = hc; hc = hn; hn = t;
    }

    k_pool_mlp<<<G, HID, 0, stream>>>(hc, batch, Nn, G, W1, b1, W2, b2, (float*)d_out);
}

// Round 7
// 615.311 us; speedup vs baseline: 4.6745x; 1.1092x over previous
//
#include <hip/hip_runtime.h>
#include <math.h>

constexpr int HID = 256;

typedef __attribute__((ext_vector_type(8))) short bf16x8;
typedef __attribute__((ext_vector_type(4))) float f32x4;

__device__ __forceinline__ float bf2f(unsigned short u){
    union { unsigned int i; float f; } v; v.i = ((unsigned int)u) << 16; return v.f;
}
__device__ __forceinline__ unsigned short f2bf(float f){
    union { float f; unsigned int i; } v; v.f = f;
    return (unsigned short)((v.i + 0x7fffu + ((v.i >> 16) & 1u)) >> 16);
}
__device__ __forceinline__ float sigm(float x){ return 1.f / (1.f + __expf(-x)); }

// bijective XCD-chunked swizzle (m204): consecutive ORIG ids land on the same XCD.
__device__ __forceinline__ int xcd_chunk(int bid, int nwg){
    int q = nwg >> 3, r = nwg & 7;
    int xcd = bid & 7, pos = bid >> 3;
    return (xcd < r) ? xcd * (q + 1) + pos : r * (q + 1) + (xcd - r) * q + pos;
}

// async global->LDS, 16B per lane. LDS dest is wave-uniform base; HW adds lane*16.
__device__ __forceinline__ void gll16(const unsigned short* g, unsigned short* l){
    __builtin_amdgcn_global_load_lds(
        (const __attribute__((address_space(1))) void*)g,
        (__attribute__((address_space(3))) void*)l, 16, 0, 0);
}

// ---------------- merged weight casts + embedding gather ----------------
__global__ void k_prep(const float* __restrict__ Wproj, const float* __restrict__ Wih,
                       const float* __restrict__ Whh, const float* __restrict__ Wg,
                       const float* __restrict__ embed, const int* __restrict__ idx,
                       unsigned short* __restrict__ wproj, unsigned short* __restrict__ wih,
                       unsigned short* __restrict__ whh, unsigned short* __restrict__ wg,
                       unsigned short* __restrict__ x0, int Nn, int EMB){
    const long n1 = (long)HID * EMB, n2 = 3L * HID * HID;
    const long n5 = (long)Nn * EMB;
    const long tot = n1 + 3 * n2 + n5;
    for (long i = blockIdx.x * (long)blockDim.x + threadIdx.x; i < tot;
         i += (long)gridDim.x * blockDim.x){
        long j = i;
        if (j < n1){ wproj[j] = f2bf(Wproj[j]); continue; }
        j -= n1;
        if (j < n2){ wih[j] = f2bf(Wih[j]); continue; }
        j -= n2;
        if (j < n2){ whh[j] = f2bf(Whh[j]); continue; }
        j -= n2;
        if (j < n2){ wg[j] = f2bf(Wg[j]); continue; }
        j -= n2;
        int row = (int)(j / EMB), k = (int)(j % EMB);
        x0[j] = f2bf(embed[(size_t)idx[row] * EMB + k]);
    }
}

// ---------------- CSR build ----------------
__global__ void k_deg(const int* __restrict__ dst, int E, int* __restrict__ deg){
    int i = blockIdx.x*blockDim.x + threadIdx.x;
    if (i < E) atomicAdd(&deg[dst[i]], 1);
}

// 3-phase parallel scan: A) per-block sums  B) scan block sums  C) scatter offsets
__global__ void k_scanA(const int* __restrict__ deg, int N, int* __restrict__ bsum){
    __shared__ int red[512];
    int b = blockIdx.x, tid = threadIdx.x;
    int i = b * 512 + tid;
    red[tid] = (i < N) ? deg[i] : 0;
    __syncthreads();
    for (int o = 256; o > 0; o >>= 1){
        if (tid < o) red[tid] += red[tid + o];
        __syncthreads();
    }
    if (tid == 0) bsum[b] = red[0];
}

__global__ void k_scanB(int* __restrict__ bsum, int nb){
    __shared__ int s[1024];
    int tid = threadIdx.x;
    s[tid] = (tid < nb) ? bsum[tid] : 0;
    __syncthreads();
    for (int o = 1; o < 1024; o <<= 1){
        int v = (tid >= o) ? s[tid - o] : 0;
        __syncthreads();
        s[tid] += v;
        __syncthreads();
    }
    if (tid < nb) bsum[tid] = (tid > 0) ? s[tid - 1] : 0;   // exclusive
    if (tid == nb) bsum[nb] = s[nb - 1];                    // total
}

__global__ void k_scanC(const int* __restrict__ deg, int N, const int* __restrict__ bsum,
                        int* __restrict__ off){
    __shared__ int s[512];
    int b = blockIdx.x, tid = threadIdx.x;
    int i = b * 512 + tid;
    int v = (i < N) ? deg[i] : 0;
    s[tid] = v;
    __syncthreads();
    for (int o = 1; o < 512; o <<= 1){
        int t = (tid >= o) ? s[tid - o] : 0;
        __syncthreads();
        s[tid] += t;
        __syncthreads();
    }
    int ex = bsum[b] + ((tid > 0) ? s[tid - 1] : 0);
    if (i < N) off[i] = ex;
    else if (i == N) off[N] = ex;   // v=0 beyond N, ex accumulates full total
}

__global__ void k_fill(const int* __restrict__ src, const int* __restrict__ dst, int E,
                       const int* __restrict__ off, int* __restrict__ cursor,
                       int* __restrict__ csr_src){
    int i = blockIdx.x*blockDim.x + threadIdx.x;
    if (i < E){
        int d = dst[i];
        int p = off[d] + atomicAdd(&cursor[d], 1);
        csr_src[p] = src[i];
    }
}

// ---------------- aggregation: 2 rows per wave, 16B/lane, 4-unrolled ----------------
__global__ void k_agg(const unsigned short* __restrict__ h, const int* __restrict__ off,
                      const int* __restrict__ csr, unsigned short* __restrict__ out, int N){
    int wave = threadIdx.x >> 6, lane = threadIdx.x & 63;
    int d = blockIdx.x * 8 + wave * 2 + (lane >> 5);
    if (d >= N) return;
    int c = (lane & 31) * 8;
    float a[8] = {};
    int s0 = off[d], s1 = off[d + 1];
    int j = s0;
    for (; j + 3 < s1; j += 4){
        int sA = csr[j], sB = csr[j + 1], sC = csr[j + 2], sD = csr[j + 3];
        bf16x8 vA = *(const bf16x8*)(h + (size_t)sA * HID + c);
        bf16x8 vB = *(const bf16x8*)(h + (size_t)sB * HID + c);
        bf16x8 vC = *(const bf16x8*)(h + (size_t)sC * HID + c);
        bf16x8 vD = *(const bf16x8*)(h + (size_t)sD * HID + c);
        #pragma unroll
        for (int q = 0; q < 8; q++)
            a[q] += (bf2f((unsigned short)vA[q]) + bf2f((unsigned short)vB[q]))
                  + (bf2f((unsigned short)vC[q]) + bf2f((unsigned short)vD[q]));
    }
    for (; j < s1; j++){
        bf16x8 vA = *(const bf16x8*)(h + (size_t)csr[j] * HID + c);
        #pragma unroll
        for (int q = 0; q < 8; q++) a[q] += bf2f((unsigned short)vA[q]);
    }
    bf16x8 o;
    #pragma unroll
    for (int q = 0; q < 8; q++) o[q] = (short)f2bf(a[q]);
    *(bf16x8*)(out + (size_t)d * HID + c) = o;
}

// ---------------- single-source GEMM: C = A @ B^T, B is [N][K] row-major, bf16 ----------------
// BM=128, BN=128, BK=32; NB=3 buffers, ONE barrier per K-step, counted vmcnt.
__global__ __launch_bounds__(256, 3) void k_mmS(
    const unsigned short* __restrict__ A, const unsigned short* __restrict__ B,
    unsigned short* __restrict__ C, int M, int N, int K,
    int nbx, long lsB, long lsC)
{
    __shared__ __align__(16) unsigned short sm[3 * 1024 * 8];   // 48 KiB
    const int tid = threadIdx.x, w = tid >> 6, l = tid & 63;
    const int wm = w >> 1, wn = w & 1, lr = l & 15, lk = l >> 4;

    const int orig = xcd_chunk(blockIdx.x, gridDim.x);
    const int layer = orig / nbx, sub = orig % nbx;
    B += layer * lsB;
    C += layer * lsC;
    const int nby = N >> 7;
    const long row0 = (long)(sub / nby) * 128;
    const int  col0 = (sub % nby) * 128;

    // staging offsets: A slots {tid, tid+256}, B slots {tid, tid+256} (region +512)
    long aoff0, aoff1, boff0, boff1;
    {
        int r0 = tid >> 2,          kc0 = tid & 3;
        int r1 = (tid + 256) >> 2,  kc1 = tid & 3;
        long g0 = row0 + r0; if (g0 > M - 1) g0 = M - 1;
        long g1 = row0 + r1; if (g1 > M - 1) g1 = M - 1;
        aoff0 = g0 * (long)K + (kc0 ^ ((r0 >> 1) & 3)) * 8;
        aoff1 = g1 * (long)K + (kc1 ^ ((r1 >> 1) & 3)) * 8;
        boff0 = (long)(col0 + r0) * K + (kc0 ^ ((r0 >> 1) & 3)) * 8;
        boff1 = (long)(col0 + r1) * K + (kc1 ^ ((r1 >> 1) & 3)) * 8;
    }
    auto STAGE = [&](int T, int buf){
        const int ka = T * 32;
        unsigned short* d = sm + (size_t)buf * 8192;
        gll16(A + aoff0 + ka, d + (0 * 256 + w * 64) * 8);
        gll16(A + aoff1 + ka, d + (1 * 256 + w * 64) * 8);
        gll16(B + boff0 + ka, d + (2 * 256 + w * 64) * 8);
        gll16(B + boff1 + ka, d + (3 * 256 + w * 64) * 8);
    };

    int raddrA[4], raddrB[4];
    #pragma unroll
    for (int i = 0; i < 4; i++){
        int ra = wm * 64 + i * 16 + lr;
        raddrA[i] = (ra * 4 + (lk ^ ((ra >> 1) & 3))) * 8;
        int rb = wn * 64 + i * 16 + lr;
        raddrB[i] = (512 + rb * 4 + (lk ^ ((rb >> 1) & 3))) * 8;
    }

    const int NT = K >> 5;
    STAGE(0, 0);
    STAGE(1, 1);

    f32x4 acc[4][4] = {};
    for (int t = 0; t < NT; t++){
        if (t < NT - 1) asm volatile("s_waitcnt vmcnt(4)" ::: "memory");
        else            asm volatile("s_waitcnt vmcnt(0)" ::: "memory");
        __builtin_amdgcn_s_barrier();
        if (t + 2 < NT) STAGE(t + 2, (t + 2) % 3);

        const unsigned short* bufp = sm + (size_t)(t % 3) * 8192;
        bf16x8 af[4], bfb[4];
        #pragma unroll
        for (int i = 0; i < 4; i++){
            af[i]  = *(const bf16x8*)(bufp + raddrA[i]);
            bfb[i] = *(const bf16x8*)(bufp + raddrB[i]);
        }
        __builtin_amdgcn_s_setprio(1);
        #pragma unroll
        for (int mi = 0; mi < 4; mi++)
            #pragma unroll
            for (int ni = 0; ni < 4; ni++)
                acc[mi][ni] = __builtin_amdgcn_mfma_f32_16x16x32_bf16(af[mi], bfb[ni], acc[mi][ni], 0, 0, 0);
        __builtin_amdgcn_s_setprio(0);
    }

    #pragma unroll
    for (int mi = 0; mi < 4; mi++)
        #pragma unroll
        for (int ni = 0; ni < 4; ni++)
            #pragma unroll
            for (int r = 0; r < 4; r++){
                long row = row0 + wm * 64 + mi * 16 + lk * 4 + r;
                if (row < M){
                    int col = col0 + wn * 64 + ni * 16 + lr;
                    C[row * (long)N + col] = f2bf(acc[mi][ni][r]);
                }
            }
}

// ---------------- fused GRU, virtual K=512 ----------------
// tiles 0-7:  A=AGG, B=Weff (gates r,z,n)  -> update aR,aZ,aI
// tiles 8-15: A=H,   B=Whh (gates r,z,n)  -> update aR,aZ,aHn
// 128x64 out-slice, 4 waves (2x2), NB=3 LDS buffers (60 KiB), ONE barrier per tile.
__global__ __launch_bounds__(256, 2) void k_gru(
    const unsigned short* __restrict__ AGG, const unsigned short* __restrict__ H,
    const unsigned short* __restrict__ WE, const unsigned short* __restrict__ WH,
    const float* __restrict__ bih, const float* __restrict__ bhh,
    unsigned short* __restrict__ HN, int M)
{
    // per buffer: A 512 slots | B 3*256 slots = 1280 slots x 16B = 20 KiB
    __shared__ __align__(16) unsigned short sm[3 * 1280 * 8];
    const int tid = threadIdx.x, w = tid >> 6, l = tid & 63;
    const int wm = w >> 1, wn = w & 1, lr = l & 15, lk = l >> 4;
    const int orig = xcd_chunk(blockIdx.x, gridDim.x);
    const long row0 = (long)(orig >> 2) * 128;
    const int  c0 = (orig & 3) * 64;

    // staging offsets (element offsets into [*][256] matrices)
    long aoff0, aoff1, boff0, boff1, boff2;
    {
        int r0 = tid >> 2,         kc = tid & 3;
        int r1 = (tid + 256) >> 2;
        long g0 = row0 + r0; if (g0 > M - 1) g0 = M - 1;
        long g1 = row0 + r1; if (g1 > M - 1) g1 = M - 1;
        aoff0 = g0 * HID + (kc ^ ((r0 >> 1) & 3)) * 8;
        aoff1 = g1 * HID + (kc ^ ((r1 >> 1) & 3)) * 8;
        int rr = tid >> 2;  // B row within 64-slice, kc same
        long sw = (kc ^ ((rr >> 1) & 3)) * 8;
        boff0 = (long)(0 * HID + c0 + rr) * HID + sw;
        boff1 = (long)(1 * HID + c0 + rr) * HID + sw;
        boff2 = (long)(2 * HID + c0 + rr) * HID + sw;
    }
    auto STAGE = [&](int T, int buf){
        const unsigned short* As = (T < 8) ? AGG : H;
        const unsigned short* Bs = (T < 8) ? WE  : WH;
        const int ka = (T & 7) * 32;
        unsigned short* d = sm + (size_t)buf * 10240;
        gll16(As + aoff0 + ka, d + (0 * 256 + w * 64) * 8);
        gll16(As + aoff1 + ka, d + (1 * 256 + w * 64) * 8);
        gll16(Bs + boff0 + ka, d + (2 * 256 + w * 64) * 8);
        gll16(Bs + boff1 + ka, d + (3 * 256 + w * 64) * 8);
        gll16(Bs + boff2 + ka, d + (4 * 256 + w * 64) * 8);
    };

    int raddrA[4], raddrB[3][2];
    #pragma unroll
    for (int i = 0; i < 4; i++){
        int ra = wm * 64 + i * 16 + lr;
        raddrA[i] = (ra * 4 + (lk ^ ((ra >> 1) & 3))) * 8;
    }
    #pragma unroll
    for (int j = 0; j < 3; j++)
        #pragma unroll
        for (int ni = 0; ni < 2; ni++){
            int rb = wn * 32 + ni * 16 + lr;
            raddrB[j][ni] = (512 + j * 256 + rb * 4 + (lk ^ ((rb >> 1) & 3))) * 8;
        }

    f32x4 aR[4][2] = {}, aZ[4][2] = {}, aI[4][2] = {}, aHn[4][2] = {};

    auto STEP = [&](const unsigned short* bufp, f32x4 (&aX)[4][2]){
        bf16x8 a[4], bb[3][2];
        #pragma unroll
        for (int i = 0; i < 4; i++) a[i] = *(const bf16x8*)(bufp + raddrA[i]);
        #pragma unroll
        for (int j = 0; j < 3; j++)
            #pragma unroll
            for (int ni = 0; ni < 2; ni++)
                bb[j][ni] = *(const bf16x8*)(bufp + raddrB[j][ni]);
        __builtin_amdgcn_s_setprio(1);
        #pragma unroll
        for (int ni = 0; ni < 2; ni++)
            #pragma unroll
            for (int mi = 0; mi < 4; mi++){
                aR[mi][ni] = __builtin_amdgcn_mfma_f32_16x16x32_bf16(a[mi], bb[0][ni], aR[mi][ni], 0, 0, 0);
                aZ[mi][ni] = __builtin_amdgcn_mfma_f32_16x16x32_bf16(a[mi], bb[1][ni], aZ[mi][ni], 0, 0, 0);
                aX[mi][ni] = __builtin_amdgcn_mfma_f32_16x16x32_bf16(a[mi], bb[2][ni], aX[mi][ni], 0, 0, 0);
            }
        __builtin_amdgcn_s_setprio(0);
    };

    STAGE(0, 0);
    STAGE(1, 1);

    #pragma unroll
    for (int t = 0; t < 16; t++){
        if (t < 15) asm volatile("s_waitcnt vmcnt(5)" ::: "memory");
        else        asm volatile("s_waitcnt vmcnt(0)" ::: "memory");
        __builtin_amdgcn_s_barrier();
        if (t + 2 < 16) STAGE(t + 2, (t + 2) % 3);
        if (t < 8) STEP(sm + (size_t)(t % 3) * 10240, aI);
        else       STEP(sm + (size_t)(t % 3) * 10240, aHn);
    }

    #pragma unroll
    for (int ni = 0; ni < 2; ni++){
        int gc = c0 + wn * 32 + ni * 16 + lr;
        float br  = bih[gc] + bhh[gc];
        float bz  = bih[HID + gc] + bhh[HID + gc];
        float bin = bih[2 * HID + gc];
        float bhn = bhh[2 * HID + gc];
        #pragma unroll
        for (int mi = 0; mi < 4; mi++)
            #pragma unroll
            for (int r = 0; r < 4; r++){
                long row = row0 + wm * 64 + mi * 16 + lk * 4 + r;
                if (row < M){
                    float rr = sigm(aR[mi][ni][r] + br);
                    float zz = sigm(aZ[mi][ni][r] + bz);
                    float nn = tanhf(aI[mi][ni][r] + bin + rr * (aHn[mi][ni][r] + bhn));
                    float hv = bf2f(H[row * HID + gc]);
                    HN[row * HID + gc] = f2bf((1.f - zz) * nn + zz * hv);
                }
            }
    }
}

// ---------------- pool (segment max over sorted batch) + MLP head ----------------
__global__ void k_pool_mlp(const unsigned short* __restrict__ h, const int* __restrict__ batch,
                           int Nn, int G,
                           const float* __restrict__ W1, const float* __restrict__ b1,
                           const float* __restrict__ W2, const float* __restrict__ b2,
                           float* __restrict__ out){
    int g = blockIdx.x;
    __shared__ float pool[HID];
    __shared__ float hid[64];

    int lo = 0, hi = Nn;
    while (lo < hi){ int mid = (lo + hi) >> 1; if (batch[mid] < g) lo = mid + 1; else hi = mid; }
    int s = lo;
    lo = s; hi = Nn;
    while (lo < hi){ int mid = (lo + hi) >> 1; if (batch[mid] < g + 1) lo = mid + 1; else hi = mid; }
    int e = lo;

    int c = threadIdx.x;
    float mx = -INFINITY;
    for (int i = s; i < e; i++) mx = fmaxf(mx, bf2f(h[(size_t)i * HID + c]));
    pool[c] = mx;
    out[(size_t)G + (size_t)g * HID + c] = mx;
    __syncthreads();

    if (c < 64){
        float sacc = b1[c];
        for (int k = 0; k < HID; k++) sacc += pool[k] * W1[c * HID + k];
        hid[c] = fmaxf(sacc, 0.f) * W2[c];
    }
    __syncthreads();
    if (c == 0){
        float sacc = b2[0];
        for (int j = 0; j < 64; j++) sacc += hid[j];
        out[g] = sacc;
    }
}

extern "C" void kernel_launch(void* const* d_in, const int* in_sizes, int n_in,
                              void* d_out, int out_size, void* d_ws, size_t ws_size,
                              hipStream_t stream){
    const int*   x_lex = (const int*)d_in[0];
    const int*   edge  = (const int*)d_in[1];
    const int*   batch = (const int*)d_in[2];
    const float* embed = (const float*)d_in[3];
    const float* Wproj = (const float*)d_in[4];
    const float* Wg    = (const float*)d_in[5];
    const float* Wih   = (const float*)d_in[6];
    const float* bih   = (const float*)d_in[7];
    const float* Whh   = (const float*)d_in[8];
    const float* bhh   = (const float*)d_in[9];
    const float* W1    = (const float*)d_in[10];
    const float* b1    = (const float*)d_in[11];
    const float* W2    = (const float*)d_in[12];
    const float* b2    = (const float*)d_in[13];

    int Nn  = in_sizes[0];
    int E   = in_sizes[1] / 2;
    int G   = out_size / (1 + HID);
    int EMB = in_sizes[4] / HID;   // W_proj is [HID, EMBED]

    const int* esrc = edge;
    const int* edst = edge + E;

    size_t HH = (size_t)HID * HID;
    unsigned short* x0    = (unsigned short*)d_ws;
    unsigned short* hA    = x0    + (size_t)Nn * EMB;
    unsigned short* hB    = hA    + (size_t)Nn * HID;
    unsigned short* aggh  = hB    + (size_t)Nn * HID;
    unsigned short* wproj = aggh  + (size_t)Nn * HID;
    unsigned short* wih   = wproj + (size_t)HID * EMB;
    unsigned short* whh   = wih   + 3 * HH;
    unsigned short* wg    = whh   + 3 * HH;   // Wg natural row-major per layer
    unsigned short* weff  = wg    + 3 * HH;   // 3 layers x [768][256]
    int* deg    = (int*)(weff + 9 * HH);
    int* cursor = deg + Nn;
    int* off    = cursor + Nn;
    int* csr    = off + Nn + 1;
    int nbScan  = (Nn + 511) / 512;
    int* bsum   = csr + E;                    // nbScan + 1 ints

    size_t ush = (size_t)Nn * (EMB + 3 * HID) + (size_t)HID * EMB + 18 * HH;
    size_t needed = ush * 2 + (size_t)(3 * Nn + 2 + E + nbScan + 1) * sizeof(int);
    if (ws_size < needed) return;

    // CSR by destination
    hipMemsetAsync(deg, 0, sizeof(int) * (size_t)(2 * Nn), stream);
    k_deg  <<<(E + 255) / 256, 256, 0, stream>>>(edst, E, deg);
    k_scanA<<<nbScan, 512, 0, stream>>>(deg, Nn, bsum);
    k_scanB<<<1, 1024, 0, stream>>>(bsum, nbScan);
    k_scanC<<<(Nn + 512) / 512, 512, 0, stream>>>(deg, Nn, bsum, off);
    k_fill <<<(E + 255) / 256, 256, 0, stream>>>(esrc, edst, E, off, cursor, csr);

    // merged weight casts + embed gather
    k_prep<<<2048, 256, 0, stream>>>(Wproj, Wih, Whh, Wg, embed, x_lex,
                                     wproj, wih, whh, wg, x0, Nn, EMB);

    // Weff_l = Wih @ Wg_l^T, all 3 layers in one dispatch (12 blocks/layer)
    k_mmS<<<36, 256, 0, stream>>>(wih, wg, weff, 3 * HID, HID, HID,
                                  12, (long)HH, (long)(3 * HH));

    int mb = (Nn + 127) / 128;

    // h0 = x0 @ wproj^T
    k_mmS<<<mb * 2, 256, 0, stream>>>(x0, wproj, hA, Nn, HID, EMB,
                                      mb * 2, 0L, 0L);

    unsigned short* hc = hA;
    unsigned short* hn = hB;
    for (int lay = 0; lay < 3; lay++){
        k_agg<<<(Nn + 7) / 8, 256, 0, stream>>>(hc, off, csr, aggh, Nn);
        k_gru<<<mb * 4, 256, 0, stream>>>(
            aggh, hc, weff + (size_t)lay * 3 * HH, whh, bih, bhh, hn, Nn);
        unsigned short* t = hc; hc = hn; hn = t;
    }

    k_pool_mlp<<<G, HID, 0, stream>>>(hc, batch, Nn, G, W1, b1, W2, b2, (float*)d_out);
}

// Round 8
// 588.802 us; speedup vs baseline: 4.8850x; 1.0450x over previous
//
#include <hip/hip_runtime.h>
#include <math.h>

constexpr int HID = 256;

typedef __attribute__((ext_vector_type(8))) short bf16x8;
typedef __attribute__((ext_vector_type(4))) float f32x4;

__device__ __forceinline__ float bf2f(unsigned short u){
    union { unsigned int i; float f; } v; v.i = ((unsigned int)u) << 16; return v.f;
}
__device__ __forceinline__ unsigned short f2bf(float f){
    union { float f; unsigned int i; } v; v.f = f;
    return (unsigned short)((v.i + 0x7fffu + ((v.i >> 16) & 1u)) >> 16);
}
__device__ __forceinline__ float sigm(float x){ return 1.f / (1.f + __expf(-x)); }

// bijective XCD-chunked swizzle (m204): consecutive ORIG ids land on the same XCD.
__device__ __forceinline__ int xcd_chunk(int bid, int nwg){
    int q = nwg >> 3, r = nwg & 7;
    int xcd = bid & 7, pos = bid >> 3;
    return (xcd < r) ? xcd * (q + 1) + pos : r * (q + 1) + (xcd - r) * q + pos;
}

// async global->LDS, 16B per lane. LDS dest is wave-uniform base; HW adds lane*16.
__device__ __forceinline__ void gll16(const unsigned short* g, unsigned short* l){
    __builtin_amdgcn_global_load_lds(
        (const __attribute__((address_space(1))) void*)g,
        (__attribute__((address_space(3))) void*)l, 16, 0, 0);
}

// ---------------- merged: weight casts + embedding gather + degree histogram ----------------
__global__ void k_prep(const float* __restrict__ Wproj, const float* __restrict__ Wih,
                       const float* __restrict__ Whh, const float* __restrict__ Wg,
                       const float* __restrict__ embed, const int* __restrict__ idx,
                       const int* __restrict__ edst, int E, int* __restrict__ deg,
                       unsigned short* __restrict__ wproj, unsigned short* __restrict__ wih,
                       unsigned short* __restrict__ whh, unsigned short* __restrict__ wg,
                       unsigned short* __restrict__ x0, int Nn, int EMB){
    const long n1 = (long)HID * EMB, n2 = 3L * HID * HID;
    const long n5 = (long)Nn * EMB;
    const long tot = n1 + 3 * n2 + n5 + E;
    for (long i = blockIdx.x * (long)blockDim.x + threadIdx.x; i < tot;
         i += (long)gridDim.x * blockDim.x){
        long j = i;
        if (j < n1){ wproj[j] = f2bf(Wproj[j]); continue; }
        j -= n1;
        if (j < n2){ wih[j] = f2bf(Wih[j]); continue; }
        j -= n2;
        if (j < n2){ whh[j] = f2bf(Whh[j]); continue; }
        j -= n2;
        if (j < n2){ wg[j] = f2bf(Wg[j]); continue; }
        j -= n2;
        if (j < n5){
            int row = (int)(j / EMB), k = (int)(j % EMB);
            x0[j] = f2bf(embed[(size_t)idx[row] * EMB + k]);
            continue;
        }
        j -= n5;
        atomicAdd(&deg[edst[j]], 1);
    }
}

// 3-phase parallel scan: A) per-block sums  B) scan block sums  C) scatter offsets
__global__ void k_scanA(const int* __restrict__ deg, int N, int* __restrict__ bsum){
    __shared__ int red[512];
    int b = blockIdx.x, tid = threadIdx.x;
    int i = b * 512 + tid;
    red[tid] = (i < N) ? deg[i] : 0;
    __syncthreads();
    for (int o = 256; o > 0; o >>= 1){
        if (tid < o) red[tid] += red[tid + o];
        __syncthreads();
    }
    if (tid == 0) bsum[b] = red[0];
}

__global__ void k_scanB(int* __restrict__ bsum, int nb){
    __shared__ int s[1024];
    int tid = threadIdx.x;
    s[tid] = (tid < nb) ? bsum[tid] : 0;
    __syncthreads();
    for (int o = 1; o < 1024; o <<= 1){
        int v = (tid >= o) ? s[tid - o] : 0;
        __syncthreads();
        s[tid] += v;
        __syncthreads();
    }
    if (tid < nb) bsum[tid] = (tid > 0) ? s[tid - 1] : 0;   // exclusive
    if (tid == nb) bsum[nb] = s[nb - 1];                    // total
}

__global__ void k_scanC(const int* __restrict__ deg, int N, const int* __restrict__ bsum,
                        int* __restrict__ off){
    __shared__ int s[512];
    int b = blockIdx.x, tid = threadIdx.x;
    int i = b * 512 + tid;
    int v = (i < N) ? deg[i] : 0;
    s[tid] = v;
    __syncthreads();
    for (int o = 1; o < 512; o <<= 1){
        int t = (tid >= o) ? s[tid - o] : 0;
        __syncthreads();
        s[tid] += t;
        __syncthreads();
    }
    int ex = bsum[b] + ((tid > 0) ? s[tid - 1] : 0);
    if (i < N) off[i] = ex;
    else if (i == N) off[N] = ex;
}

__global__ void k_fill(const int* __restrict__ src, const int* __restrict__ dst, int E,
                       const int* __restrict__ off, int* __restrict__ cursor,
                       int* __restrict__ csr_src){
    int i = blockIdx.x*blockDim.x + threadIdx.x;
    if (i < E){
        int d = dst[i];
        int p = off[d] + atomicAdd(&cursor[d], 1);
        csr_src[p] = src[i];
    }
}

// ---------------- aggregation: 2 rows per wave, 16B/lane, 4-unrolled ----------------
__global__ void k_agg(const unsigned short* __restrict__ h, const int* __restrict__ off,
                      const int* __restrict__ csr, unsigned short* __restrict__ out, int N){
    int wave = threadIdx.x >> 6, lane = threadIdx.x & 63;
    int d = blockIdx.x * 8 + wave * 2 + (lane >> 5);
    if (d >= N) return;
    int c = (lane & 31) * 8;
    float a[8] = {};
    int s0 = off[d], s1 = off[d + 1];
    int j = s0;
    for (; j + 3 < s1; j += 4){
        int sA = csr[j], sB = csr[j + 1], sC = csr[j + 2], sD = csr[j + 3];
        bf16x8 vA = *(const bf16x8*)(h + (size_t)sA * HID + c);
        bf16x8 vB = *(const bf16x8*)(h + (size_t)sB * HID + c);
        bf16x8 vC = *(const bf16x8*)(h + (size_t)sC * HID + c);
        bf16x8 vD = *(const bf16x8*)(h + (size_t)sD * HID + c);
        #pragma unroll
        for (int q = 0; q < 8; q++)
            a[q] += (bf2f((unsigned short)vA[q]) + bf2f((unsigned short)vB[q]))
                  + (bf2f((unsigned short)vC[q]) + bf2f((unsigned short)vD[q]));
    }
    for (; j < s1; j++){
        bf16x8 vA = *(const bf16x8*)(h + (size_t)csr[j] * HID + c);
        #pragma unroll
        for (int q = 0; q < 8; q++) a[q] += bf2f((unsigned short)vA[q]);
    }
    bf16x8 o;
    #pragma unroll
    for (int q = 0; q < 8; q++) o[q] = (short)f2bf(a[q]);
    *(bf16x8*)(out + (size_t)d * HID + c) = o;
}

// ---------------- single-source GEMM: C = A @ B^T, B is [N][K] row-major, bf16 ----------------
// BM=128, BN=128, BK=32; NB=3 buffers, ONE barrier per K-step, counted vmcnt.
__global__ __launch_bounds__(256, 3) void k_mmS(
    const unsigned short* __restrict__ A, const unsigned short* __restrict__ B,
    unsigned short* __restrict__ C, int M, int N, int K,
    int nbx, long lsB, long lsC)
{
    __shared__ __align__(16) unsigned short sm[3 * 1024 * 8];   // 48 KiB
    const int tid = threadIdx.x, w = tid >> 6, l = tid & 63;
    const int wm = w >> 1, wn = w & 1, lr = l & 15, lk = l >> 4;

    const int orig = xcd_chunk(blockIdx.x, gridDim.x);
    const int layer = orig / nbx, sub = orig % nbx;
    B += layer * lsB;
    C += layer * lsC;
    const int nby = N >> 7;
    const long row0 = (long)(sub / nby) * 128;
    const int  col0 = (sub % nby) * 128;

    long aoff0, aoff1, boff0, boff1;
    {
        int r0 = tid >> 2,          kc0 = tid & 3;
        int r1 = (tid + 256) >> 2,  kc1 = tid & 3;
        long g0 = row0 + r0; if (g0 > M - 1) g0 = M - 1;
        long g1 = row0 + r1; if (g1 > M - 1) g1 = M - 1;
        aoff0 = g0 * (long)K + (kc0 ^ ((r0 >> 1) & 3)) * 8;
        aoff1 = g1 * (long)K + (kc1 ^ ((r1 >> 1) & 3)) * 8;
        boff0 = (long)(col0 + r0) * K + (kc0 ^ ((r0 >> 1) & 3)) * 8;
        boff1 = (long)(col0 + r1) * K + (kc1 ^ ((r1 >> 1) & 3)) * 8;
    }
    auto STAGE = [&](int T, int buf){
        const int ka = T * 32;
        unsigned short* d = sm + (size_t)buf * 8192;
        gll16(A + aoff0 + ka, d + (0 * 256 + w * 64) * 8);
        gll16(A + aoff1 + ka, d + (1 * 256 + w * 64) * 8);
        gll16(B + boff0 + ka, d + (2 * 256 + w * 64) * 8);
        gll16(B + boff1 + ka, d + (3 * 256 + w * 64) * 8);
    };

    int raddrA[4], raddrB[4];
    #pragma unroll
    for (int i = 0; i < 4; i++){
        int ra = wm * 64 + i * 16 + lr;
        raddrA[i] = (ra * 4 + (lk ^ ((ra >> 1) & 3))) * 8;
        int rb = wn * 64 + i * 16 + lr;
        raddrB[i] = (512 + rb * 4 + (lk ^ ((rb >> 1) & 3))) * 8;
    }

    const int NT = K >> 5;
    STAGE(0, 0);
    STAGE(1, 1);

    f32x4 acc[4][4] = {};
    for (int t = 0; t < NT; t++){
        if (t < NT - 1) asm volatile("s_waitcnt vmcnt(4)" ::: "memory");
        else            asm volatile("s_waitcnt vmcnt(0)" ::: "memory");
        __builtin_amdgcn_s_barrier();
        if (t + 2 < NT) STAGE(t + 2, (t + 2) % 3);

        const unsigned short* bufp = sm + (size_t)(t % 3) * 8192;
        bf16x8 af[4], bfb[4];
        #pragma unroll
        for (int i = 0; i < 4; i++){
            af[i]  = *(const bf16x8*)(bufp + raddrA[i]);
            bfb[i] = *(const bf16x8*)(bufp + raddrB[i]);
        }
        __builtin_amdgcn_s_setprio(1);
        #pragma unroll
        for (int mi = 0; mi < 4; mi++)
            #pragma unroll
            for (int ni = 0; ni < 4; ni++)
                acc[mi][ni] = __builtin_amdgcn_mfma_f32_16x16x32_bf16(af[mi], bfb[ni], acc[mi][ni], 0, 0, 0);
        __builtin_amdgcn_s_setprio(0);
    }

    #pragma unroll
    for (int mi = 0; mi < 4; mi++)
        #pragma unroll
        for (int ni = 0; ni < 4; ni++)
            #pragma unroll
            for (int r = 0; r < 4; r++){
                long row = row0 + wm * 64 + mi * 16 + lk * 4 + r;
                if (row < M){
                    int col = col0 + wn * 64 + ni * 16 + lr;
                    C[row * (long)N + col] = f2bf(acc[mi][ni][r]);
                }
            }
}

// ---------------- fused GRU, virtual K=512, occupancy-tiled ----------------
// Block = 64 rows x 64 cols x {r,z,n} gate-sets; 4 waves, wave tile 32x32/set.
// tiles 0-7: A=AGG vs WE (aR,aZ,aI); tiles 8-15: A=H vs WH (aR,aZ,aHn).
// NB=3 x 16 KiB LDS = 48 KiB -> 3 blocks/CU (with launch_bounds(256,3)).
// Per thread-wave STAGE: 1 A + 3 B gll16 (uniform) -> vmcnt(4) counted pipeline.
__global__ __launch_bounds__(256, 3) void k_gru(
    const unsigned short* __restrict__ AGG, const unsigned short* __restrict__ H,
    const unsigned short* __restrict__ WE, const unsigned short* __restrict__ WH,
    const float* __restrict__ bih, const float* __restrict__ bhh,
    unsigned short* __restrict__ HN, int M)
{
    // buffer: A 256 slots | B 3*256 slots = 1024 slots * 16B = 16 KiB
    __shared__ __align__(16) unsigned short sm[3 * 1024 * 8];
    const int tid = threadIdx.x, w = tid >> 6, l = tid & 63;
    const int wm = w >> 1, wn = w & 1, lr = l & 15, lk = l >> 4;
    const int orig = xcd_chunk(blockIdx.x, gridDim.x);
    const long row0 = (long)(orig >> 2) * 64;
    const int  c0 = (orig & 3) * 64;

    long aoff, boff[3];
    {
        int r0 = tid >> 2, kc = tid & 3;
        long g0 = row0 + r0; if (g0 > M - 1) g0 = M - 1;
        int sw = (kc ^ ((r0 >> 1) & 3)) * 8;
        aoff = g0 * HID + sw;
        #pragma unroll
        for (int q = 0; q < 3; q++)
            boff[q] = (long)(q * HID + c0 + r0) * HID + sw;
    }
    auto STAGE = [&](int T, int buf){
        const unsigned short* As = (T < 8) ? AGG : H;
        const unsigned short* Bs = (T < 8) ? WE  : WH;
        const int ka = (T & 7) * 32;
        unsigned short* d = sm + (size_t)buf * 8192;
        gll16(As + aoff + ka, d + (w * 64) * 8);
        #pragma unroll
        for (int q = 0; q < 3; q++)
            gll16(Bs + boff[q] + ka, d + (256 + q * 256 + w * 64) * 8);
    };

    int raddrA[2], raddrB[3][2];
    #pragma unroll
    for (int i = 0; i < 2; i++){
        int ra = wm * 32 + i * 16 + lr;
        raddrA[i] = (ra * 4 + (lk ^ ((ra >> 1) & 3))) * 8;
    }
    #pragma unroll
    for (int j = 0; j < 3; j++)
        #pragma unroll
        for (int ni = 0; ni < 2; ni++){
            int rb = wn * 32 + ni * 16 + lr;
            raddrB[j][ni] = (256 + j * 256 + rb * 4 + (lk ^ ((rb >> 1) & 3))) * 8;
        }

    f32x4 aR[2][2] = {}, aZ[2][2] = {}, aI[2][2] = {}, aHn[2][2] = {};

    STAGE(0, 0);
    STAGE(1, 1);

    #pragma unroll
    for (int t = 0; t < 16; t++){
        if (t < 15) asm volatile("s_waitcnt vmcnt(4)" ::: "memory");
        else        asm volatile("s_waitcnt vmcnt(0)" ::: "memory");
        __builtin_amdgcn_s_barrier();
        if (t + 2 < 16) STAGE(t + 2, (t + 2) % 3);

        const unsigned short* bufp = sm + (size_t)(t % 3) * 8192;
        bf16x8 a[2], bb[3][2];
        #pragma unroll
        for (int i = 0; i < 2; i++) a[i] = *(const bf16x8*)(bufp + raddrA[i]);
        #pragma unroll
        for (int j = 0; j < 3; j++)
            #pragma unroll
            for (int ni = 0; ni < 2; ni++)
                bb[j][ni] = *(const bf16x8*)(bufp + raddrB[j][ni]);

        __builtin_amdgcn_s_setprio(1);
        #pragma unroll
        for (int ni = 0; ni < 2; ni++)
            #pragma unroll
            for (int mi = 0; mi < 2; mi++){
                aR[mi][ni] = __builtin_amdgcn_mfma_f32_16x16x32_bf16(a[mi], bb[0][ni], aR[mi][ni], 0, 0, 0);
                aZ[mi][ni] = __builtin_amdgcn_mfma_f32_16x16x32_bf16(a[mi], bb[1][ni], aZ[mi][ni], 0, 0, 0);
                if (t < 8)
                    aI[mi][ni]  = __builtin_amdgcn_mfma_f32_16x16x32_bf16(a[mi], bb[2][ni], aI[mi][ni], 0, 0, 0);
                else
                    aHn[mi][ni] = __builtin_amdgcn_mfma_f32_16x16x32_bf16(a[mi], bb[2][ni], aHn[mi][ni], 0, 0, 0);
            }
        __builtin_amdgcn_s_setprio(0);
    }

    #pragma unroll
    for (int ni = 0; ni < 2; ni++){
        int gc = c0 + wn * 32 + ni * 16 + lr;
        float br  = bih[gc] + bhh[gc];
        float bz  = bih[HID + gc] + bhh[HID + gc];
        float bin = bih[2 * HID + gc];
        float bhn = bhh[2 * HID + gc];
        #pragma unroll
        for (int mi = 0; mi < 2; mi++)
            #pragma unroll
            for (int r = 0; r < 4; r++){
                long row = row0 + wm * 32 + mi * 16 + lk * 4 + r;
                if (row < M){
                    float rr = sigm(aR[mi][ni][r] + br);
                    float zz = sigm(aZ[mi][ni][r] + bz);
                    float nn = tanhf(aI[mi][ni][r] + bin + rr * (aHn[mi][ni][r] + bhn));
                    float hv = bf2f(H[row * HID + gc]);
                    HN[row * HID + gc] = f2bf((1.f - zz) * nn + zz * hv);
                }
            }
    }
}

// ---------------- pool (segment max over sorted batch) + MLP head ----------------
__global__ void k_pool_mlp(const unsigned short* __restrict__ h, const int* __restrict__ batch,
                           int Nn, int G,
                           const float* __restrict__ W1, const float* __restrict__ b1,
                           const float* __restrict__ W2, const float* __restrict__ b2,
                           float* __restrict__ out){
    int g = blockIdx.x;
    __shared__ float pool[HID];
    __shared__ float hid[64];

    int lo = 0, hi = Nn;
    while (lo < hi){ int mid = (lo + hi) >> 1; if (batch[mid] < g) lo = mid + 1; else hi = mid; }
    int s = lo;
    lo = s; hi = Nn;
    while (lo < hi){ int mid = (lo + hi) >> 1; if (batch[mid] < g + 1) lo = mid + 1; else hi = mid; }
    int e = lo;

    int c = threadIdx.x;
    float mx = -INFINITY;
    for (int i = s; i < e; i++) mx = fmaxf(mx, bf2f(h[(size_t)i * HID + c]));
    pool[c] = mx;
    out[(size_t)G + (size_t)g * HID + c] = mx;
    __syncthreads();

    if (c < 64){
        float sacc = b1[c];
        for (int k = 0; k < HID; k++) sacc += pool[k] * W1[c * HID + k];
        hid[c] = fmaxf(sacc, 0.f) * W2[c];
    }
    __syncthreads();
    if (c == 0){
        float sacc = b2[0];
        for (int j = 0; j < 64; j++) sacc += hid[j];
        out[g] = sacc;
    }
}

extern "C" void kernel_launch(void* const* d_in, const int* in_sizes, int n_in,
                              void* d_out, int out_size, void* d_ws, size_t ws_size,
                              hipStream_t stream){
    const int*   x_lex = (const int*)d_in[0];
    const int*   edge  = (const int*)d_in[1];
    const int*   batch = (const int*)d_in[2];
    const float* embed = (const float*)d_in[3];
    const float* Wproj = (const float*)d_in[4];
    const float* Wg    = (const float*)d_in[5];
    const float* Wih   = (const float*)d_in[6];
    const float* bih   = (const float*)d_in[7];
    const float* Whh   = (const float*)d_in[8];
    const float* bhh   = (const float*)d_in[9];
    const float* W1    = (const float*)d_in[10];
    const float* b1    = (const float*)d_in[11];
    const float* W2    = (const float*)d_in[12];
    const float* b2    = (const float*)d_in[13];

    int Nn  = in_sizes[0];
    int E   = in_sizes[1] / 2;
    int G   = out_size / (1 + HID);
    int EMB = in_sizes[4] / HID;   // W_proj is [HID, EMBED]

    const int* esrc = edge;
    const int* edst = edge + E;

    size_t HH = (size_t)HID * HID;
    unsigned short* x0    = (unsigned short*)d_ws;
    unsigned short* hA    = x0    + (size_t)Nn * EMB;
    unsigned short* hB    = hA    + (size_t)Nn * HID;
    unsigned short* aggh  = hB    + (size_t)Nn * HID;
    unsigned short* wproj = aggh  + (size_t)Nn * HID;
    unsigned short* wih   = wproj + (size_t)HID * EMB;
    unsigned short* whh   = wih   + 3 * HH;
    unsigned short* wg    = whh   + 3 * HH;   // Wg natural row-major per layer
    unsigned short* weff  = wg    + 3 * HH;   // 3 layers x [768][256]
    int* deg    = (int*)(weff + 9 * HH);
    int* cursor = deg + Nn;
    int* off    = cursor + Nn;
    int* csr    = off + Nn + 1;
    int nbScan  = (Nn + 511) / 512;
    int* bsum   = csr + E;                    // nbScan + 1 ints

    size_t ush = (size_t)Nn * (EMB + 3 * HID) + (size_t)HID * EMB + 18 * HH;
    size_t needed = ush * 2 + (size_t)(3 * Nn + 2 + E + nbScan + 1) * sizeof(int);
    if (ws_size < needed) return;

    // merged weight casts + embed gather + degree histogram
    hipMemsetAsync(deg, 0, sizeof(int) * (size_t)(2 * Nn), stream);
    k_prep<<<2048, 256, 0, stream>>>(Wproj, Wih, Whh, Wg, embed, x_lex,
                                     edst, E, deg,
                                     wproj, wih, whh, wg, x0, Nn, EMB);
    k_scanA<<<nbScan, 512, 0, stream>>>(deg, Nn, bsum);
    k_scanB<<<1, 1024, 0, stream>>>(bsum, nbScan);
    k_scanC<<<(Nn + 512) / 512, 512, 0, stream>>>(deg, Nn, bsum, off);
    k_fill <<<(E + 255) / 256, 256, 0, stream>>>(esrc, edst, E, off, cursor, csr);

    // Weff_l = Wih @ Wg_l^T, all 3 layers in one dispatch (12 blocks/layer)
    k_mmS<<<36, 256, 0, stream>>>(wih, wg, weff, 3 * HID, HID, HID,
                                  12, (long)HH, (long)(3 * HH));

    int mb = (Nn + 127) / 128;

    // h0 = x0 @ wproj^T
    k_mmS<<<mb * 2, 256, 0, stream>>>(x0, wproj, hA, Nn, HID, EMB,
                                      mb * 2, 0L, 0L);

    int gruBlocks = ((Nn + 63) / 64) * 4;

    unsigned short* hc = hA;
    unsigned short* hn = hB;
    for (int lay = 0; lay < 3; lay++){
        k_agg<<<(Nn + 7) / 8, 256, 0, stream>>>(hc, off, csr, aggh, Nn);
        k_gru<<<gruBlocks, 256, 0, stream>>>(
            aggh, hc, weff + (size_t)lay * 3 * HH, whh, bih, bhh, hn, Nn);
        unsigned short* t = hc; hc = hn; hn = t;
    }

    k_pool_mlp<<<G, HID, 0, stream>>>(hc, batch, Nn, G, W1, b1, W2, b2, (float*)d_out);
}